// Round 13
// baseline (55885.687 us; speedup 1.0000x reference)
//
#include <hip/hip_runtime.h>

// ---------------------------------------------------------------------------
// Transformer_90426241450054 — MI355X (round 13)
// Numerics: proven 3-mult split-f16 pairs (x ~= hi + lo*2^-11, fp32 parity).
// conv13: conv4 geometry (128x128 tile, 4 waves), A halo in LDS (32 KB,
// swizzled), B global(L1/L2)->REGISTERS ping-pong with function-scope arrays
// + constant indices (no scratch), barriers ONLY at kb boundaries (8 total).
// Tap-skip, setprio, XCD swizzle, nontemporal streamed stores.
// ---------------------------------------------------------------------------

typedef _Float16 f16;
typedef __attribute__((ext_vector_type(8))) _Float16 f16x8;
typedef __attribute__((ext_vector_type(4))) _Float16 f16x4;
typedef __attribute__((ext_vector_type(4))) float f32x4;

static constexpr long kSC = 14155776;               // score elems = 2*512*13824
static constexpr float kDS = 4.8828125e-4f;         // 2^-11

#define MFMA16(a, b, c) __builtin_amdgcn_mfma_f32_16x16x32_f16((a), (b), (c), 0, 0, 0)

__device__ __forceinline__ void gl16(const void* g, void* l) {
  __builtin_amdgcn_global_load_lds((const __attribute__((address_space(1))) void*)g,
                                   (__attribute__((address_space(3))) void*)l,
                                   16, 0, 0);
}

__device__ __forceinline__ float wave_sum_f(float x) {
#pragma unroll
  for (int m = 32; m; m >>= 1) x += __shfl_xor(x, m);
  return x;
}

__device__ __forceinline__ void split2(float x, f16* h, f16* l) {
  f16 hh = (f16)x;
  *h = hh;
  *l = (f16)((x - (float)hh) * 2048.0f);
}

__device__ __forceinline__ float rec2(f16 h, f16 l) {
  return (float)h + (float)l * kDS;
}

__device__ __forceinline__ float gelu_exact(float x) {
  return 0.5f * x * (1.0f + erff(x * 0.70710678118654752f));
}

// ---------------- weight split: [G][Ci][Co] f32 -> [G][CoTot][Ci] pair ------
__global__ __launch_bounds__(256) void wsplit_kernel(
    const float* __restrict__ src, f16* __restrict__ hi, f16* __restrict__ lo,
    int G, int Ci, int Co, int CoTot, int co0) {
  long n = (long)G * Ci * Co;
  long i = (long)blockIdx.x * 256 + threadIdx.x;
  if (i >= n) return;
  int co = (int)(i % Co);
  long t = i / Co;
  int ci = (int)(t % Ci);
  int g  = (int)(t / Ci);
  float x = src[i];
  long o = ((long)g * CoTot + co0 + co) * Ci + ci;
  split2(x, hi + o, lo + o);
}

// ---------------- bias concat (q,k,v -> 768) -------------------------------
__global__ __launch_bounds__(256) void bpack_kernel(
    const float* __restrict__ bq, const float* __restrict__ bk,
    const float* __restrict__ bv, float* __restrict__ dst) {
  int i = blockIdx.x * 256 + threadIdx.x;
  if (i < 256) dst[i] = bq[i];
  else if (i < 512) dst[i] = bk[i - 256];
  else if (i < 768) dst[i] = bv[i - 512];
}

// ---------------- embedding + pos -> H pair --------------------------------
__global__ __launch_bounds__(256) void embed_kernel(
    const int* __restrict__ code, const int* __restrict__ ncode,
    const float* __restrict__ emb, const float* __restrict__ pos,
    f16* __restrict__ Hh, f16* __restrict__ Hl) {
  int tok = blockIdx.x;            // g*8192 + s*512 + vox
  int e = threadIdx.x;
  int g = tok >> 13;
  int rem = tok & 8191;
  int s = rem >> 9;
  int vox = rem & 511;
  int n = g / 3, c = g - 3 * n;
  int idx;
  if (s < 8) idx = code[((n * 8 + s) * 3 + c) * 512 + vox];
  else       idx = ncode[((n * 9 + (s - 8)) * 3 + c) * 512 + vox];
  float val = emb[idx * 256 + e] + pos[s * 256 + e];
  long o = (long)tok * 256 + e;
  split2(val, Hh + o, Hl + o);
}

// ---------------- conv3d 3x3x3 SAME, v13 (B in registers, few barriers) ----
// Block: 256 thr / 4 waves (2x2); tile 128 rows (2 u-planes) x 128 couts.
// Wave tile 64x64: 48 MFMA + 8 LDS A-reads + 8 global B-loads per phase.
// LDS 32 KB: A pair halo only (swizzled). B: register ping-pong with
// function-scope arrays, constant indices, dedicated per-buffer lambdas.
// Barriers only around the kb-boundary A restage.
template <int CIN, int COUTT, int ACT, int RESID>
__global__ __launch_bounds__(256, 2) void conv13_kernel(
    const f16* __restrict__ Xh, const f16* __restrict__ Xl, long xz_s, int xr,
    const f16* __restrict__ Wh, const f16* __restrict__ Wl,
    const float* __restrict__ bias,
    f16* __restrict__ Yh, f16* __restrict__ Yl, long yz_s, int yr, int nz) {
  constexpr int KB = CIN / 32;
  constexpr int NY = COUTT / 128;
  __shared__ __align__(16) f16 lsA[16384];   // 32 KB: A0 [0,8192) A1 [8192,16384)

  const int nwg = 64 * NY * nz;
  const int q = nwg >> 3;
  const int bid = blockIdx.x;
  const int wg = (bid & 7) * q + (bid >> 3);
  const int y = wg / (64 * nz);
  const int rem = wg - y * (64 * nz);
  const int z = rem >> 6;
  const int mt = rem & 63;
  const int img = mt >> 2, up = mt & 3;
  const int u0 = up * 2;
  const int coutb0 = y * 128;

  const int tid = threadIdx.x;
  const int wid = tid >> 6, lane = tid & 63;
  const int wm = wid >> 1, wn = wid & 1;
  const int l15 = lane & 15, lk = lane >> 4;

  const long xz = (long)z * xz_s;
  const long yz = (long)z * yz_s;

  f32x4 aA[4][4], aB[4][4];
#pragma unroll
  for (int mf = 0; mf < 4; ++mf)
#pragma unroll
    for (int nf = 0; nf < 4; ++nf) {
      float bv = bias[coutb0 + wn * 64 + nf * 16 + l15];
      aA[mf][nf] = (f32x4){bv, bv, bv, bv};
      aB[mf][nf] = (f32x4){0.f, 0.f, 0.f, 0.f};
    }

  const int swrow = tid >> 2;                       // A staging row
  const int sswz = (tid & 3) ^ ((tid >> 3) & 3);    // staged col swizzle

  auto stageA = [&](int kb) {
#pragma unroll
    for (int j = 0; j < 4; ++j) {
      const int uu = u0 - 1 + j;
      if (uu < 0 || uu >= 8) continue;  // block-uniform
      const long g = xz + ((long)(img * 512 + uu * 64 + swrow)) * (long)xr
                     + kb * 32 + sswz * 8;
      gl16(Xh + g, &lsA[j * 2048 + tid * 8]);
      gl16(Xl + g, &lsA[8192 + j * 2048 + tid * 8]);
    }
  };

  // B register ping-pong: function-scope arrays, constant indices only.
  f16x8 b0h[4], b0l[4], b1h[4], b1l[4];
  const long wbase = ((long)coutb0 + wn * 64 + l15) * (long)CIN + lk * 8;

  auto loadB0 = [&](int o, int kb) {
    const int du = o / 9 - 1;
    if ((unsigned)(u0 + wm + du) >= 8u) return;     // wave-uniform skip
    const long base = (long)o * COUTT * (long)CIN + wbase + kb * 32;
#pragma unroll
    for (int nf = 0; nf < 4; ++nf) {
      b0h[nf] = *(const f16x8*)(Wh + base + (long)nf * 16 * CIN);
      b0l[nf] = *(const f16x8*)(Wl + base + (long)nf * 16 * CIN);
    }
  };
  auto loadB1 = [&](int o, int kb) {
    const int du = o / 9 - 1;
    if ((unsigned)(u0 + wm + du) >= 8u) return;
    const long base = (long)o * COUTT * (long)CIN + wbase + kb * 32;
#pragma unroll
    for (int nf = 0; nf < 4; ++nf) {
      b1h[nf] = *(const f16x8*)(Wh + base + (long)nf * 16 * CIN);
      b1l[nf] = *(const f16x8*)(Wl + base + (long)nf * 16 * CIN);
    }
  };
  auto computeB0 = [&](int o) {
    const int du = o / 9 - 1, dv = (o / 3) % 3 - 1, dw = o % 3 - 1;
    const int gu = u0 + wm + du;
    if ((unsigned)gu >= 8u) return;                 // wave-uniform tap skip
    const int p = wm + 1 + du;
    __builtin_amdgcn_s_setprio(1);
#pragma unroll
    for (int mf = 0; mf < 4; ++mf) {
      const int vrow = mf * 16 + l15;
      const int vv = (vrow >> 3) + dv, ww = (vrow & 7) + dw;
      const bool ok = ((unsigned)vv < 8u) && ((unsigned)ww < 8u);
      f16x8 ah = {0, 0, 0, 0, 0, 0, 0, 0};
      f16x8 al = {0, 0, 0, 0, 0, 0, 0, 0};
      if (ok) {
        const int lrow = p * 64 + vv * 8 + ww;
        const int sw = lk ^ ((lrow >> 1) & 3);
        ah = *(const f16x8*)&lsA[lrow * 32 + sw * 8];
        al = *(const f16x8*)&lsA[8192 + lrow * 32 + sw * 8];
      }
#pragma unroll
      for (int nf = 0; nf < 4; ++nf) {
        aA[mf][nf] = MFMA16(ah, b0h[nf], aA[mf][nf]);
        aB[mf][nf] = MFMA16(ah, b0l[nf], aB[mf][nf]);
        aB[mf][nf] = MFMA16(al, b0h[nf], aB[mf][nf]);
      }
    }
    __builtin_amdgcn_s_setprio(0);
  };
  auto computeB1 = [&](int o) {
    const int du = o / 9 - 1, dv = (o / 3) % 3 - 1, dw = o % 3 - 1;
    const int gu = u0 + wm + du;
    if ((unsigned)gu >= 8u) return;
    const int p = wm + 1 + du;
    __builtin_amdgcn_s_setprio(1);
#pragma unroll
    for (int mf = 0; mf < 4; ++mf) {
      const int vrow = mf * 16 + l15;
      const int vv = (vrow >> 3) + dv, ww = (vrow & 7) + dw;
      const bool ok = ((unsigned)vv < 8u) && ((unsigned)ww < 8u);
      f16x8 ah = {0, 0, 0, 0, 0, 0, 0, 0};
      f16x8 al = {0, 0, 0, 0, 0, 0, 0, 0};
      if (ok) {
        const int lrow = p * 64 + vv * 8 + ww;
        const int sw = lk ^ ((lrow >> 1) & 3);
        ah = *(const f16x8*)&lsA[lrow * 32 + sw * 8];
        al = *(const f16x8*)&lsA[8192 + lrow * 32 + sw * 8];
      }
#pragma unroll
      for (int nf = 0; nf < 4; ++nf) {
        aA[mf][nf] = MFMA16(ah, b1h[nf], aA[mf][nf]);
        aB[mf][nf] = MFMA16(ah, b1l[nf], aB[mf][nf]);
        aB[mf][nf] = MFMA16(al, b1h[nf], aB[mf][nf]);
      }
    }
    __builtin_amdgcn_s_setprio(0);
  };

  // prologue
  stageA(0);
  loadB0(0, 0);
  __syncthreads();                                  // A[0] visible

  int o = 0, kb = 0;
#pragma unroll 1
  for (int it = 0; it < (KB * 27) / 2; ++it) {
    // half-step A: prefetch next into b1, compute b0
    {
      int on = o + 1, kbn = kb;
      if (on == 27) { on = 0; kbn = kb + 1; }
      if (kbn < KB) loadB1(on, kbn);
      computeB0(o);
      if (o == 26 && kbn < KB) {
        __syncthreads();                            // A[kb] readers done
        stageA(kbn);
        __syncthreads();                            // A[kbn] visible
      }
      o = on; kb = kbn;
    }
    // half-step B: prefetch next into b0, compute b1
    {
      int on = o + 1, kbn = kb;
      if (on == 27) { on = 0; kbn = kb + 1; }
      if (kbn < KB) loadB0(on, kbn);
      computeB1(o);
      if (o == 26 && kbn < KB) {
        __syncthreads();
        stageA(kbn);
        __syncthreads();
      }
      o = on; kb = kbn;
    }
  }
  __syncthreads();                                  // before LDS reuse

  // epilogue: 4 passes of 32 rows through LDS f32 [32][132] (verified in R11)
  float* sY = (float*)lsA;
#pragma unroll 1
  for (int qp = 0; qp < 4; ++qp) {
    if (wm == (qp >> 1)) {
#pragma unroll
      for (int mm = 0; mm < 2; ++mm) {
        const int mf = (qp & 1) * 2 + mm;
#pragma unroll
        for (int nf = 0; nf < 4; ++nf)
#pragma unroll
          for (int j = 0; j < 4; ++j) {
            const int lrow = mm * 16 + lk * 4 + j;
            const int col = wn * 64 + nf * 16 + l15;
            sY[lrow * 132 + col] = aA[mf][nf][j] + aB[mf][nf][j] * kDS;
          }
      }
    }
    __syncthreads();
    const int row = tid >> 3;                       // 0..31
    const int c0 = (tid & 7) * 16;
    const int rblk = qp * 32 + row;
    const long grow = (long)img * 512 + (u0 + (rblk >> 6)) * 64 + (rblk & 63);
    const long gidx = yz + grow * (long)yr + coutb0 + c0;
    float yv[16];
#pragma unroll
    for (int i2 = 0; i2 < 16; ++i2) yv[i2] = sY[row * 132 + c0 + i2];
    if (ACT) {
#pragma unroll
      for (int i2 = 0; i2 < 16; ++i2) yv[i2] = gelu_exact(yv[i2]);
    }
    if (RESID) {
      f16x8 r0h = *(const f16x8*)&Yh[gidx];
      f16x8 r1h = *(const f16x8*)&Yh[gidx + 8];
      f16x8 r0l = *(const f16x8*)&Yl[gidx];
      f16x8 r1l = *(const f16x8*)&Yl[gidx + 8];
#pragma unroll
      for (int i2 = 0; i2 < 8; ++i2) {
        yv[i2] += rec2(r0h[i2], r0l[i2]);
        yv[8 + i2] += rec2(r1h[i2], r1l[i2]);
      }
    }
    f16x8 h0, h1, l0, l1;
#pragma unroll
    for (int i2 = 0; i2 < 8; ++i2) {
      f16 a, b;
      split2(yv[i2], &a, &b); h0[i2] = a; l0[i2] = b;
      split2(yv[8 + i2], &a, &b); h1[i2] = a; l1[i2] = b;
    }
    if (RESID) {
      *(f16x8*)&Yh[gidx] = h0;
      *(f16x8*)&Yh[gidx + 8] = h1;
      *(f16x8*)&Yl[gidx] = l0;
      *(f16x8*)&Yl[gidx + 8] = l1;
    } else {
      __builtin_nontemporal_store(h0, (f16x8*)&Yh[gidx]);
      __builtin_nontemporal_store(h1, (f16x8*)&Yh[gidx + 8]);
      __builtin_nontemporal_store(l0, (f16x8*)&Yl[gidx]);
      __builtin_nontemporal_store(l1, (f16x8*)&Yl[gidx + 8]);
    }
    __syncthreads();
  }
}

// ---------------- plain GEMM (classifier), pair in, pair or f32 out --------
template <int K_, int COUT, bool F32OUT>
__global__ __launch_bounds__(256) void gemm_kernel(
    const f16* __restrict__ Xh, const f16* __restrict__ Xl,
    const f16* __restrict__ Wh, const f16* __restrict__ Wl,
    const float* __restrict__ bias,
    f16* __restrict__ Yh, f16* __restrict__ Yl, float* __restrict__ Yf) {
  const int m0 = blockIdx.x * 64;
  const int coutb = blockIdx.y * 64;
  const int tid = threadIdx.x;
  const int wid = tid >> 6, lane = tid & 63;
  const int l15 = lane & 15, lk = lane >> 4;
  const int arow = m0 + wid * 16 + l15;

  f32x4 accA[4], accB[4];
#pragma unroll
  for (int cg = 0; cg < 4; ++cg) {
    float bv = bias[coutb + cg * 16 + l15];
    accA[cg] = (f32x4){bv, bv, bv, bv};
    accB[cg] = (f32x4){0.f, 0.f, 0.f, 0.f};
  }
  const f16* pah = Xh + (long)arow * K_ + lk * 8;
  const f16* pal = Xl + (long)arow * K_ + lk * 8;
  const f16* pbh = Wh + ((long)coutb + l15) * K_ + lk * 8;
  const f16* pbl = Wl + ((long)coutb + l15) * K_ + lk * 8;
#pragma unroll 2
  for (int kb = 0; kb < K_ / 32; ++kb) {
    f16x8 ah = *(const f16x8*)(pah + kb * 32);
    f16x8 al = *(const f16x8*)(pal + kb * 32);
#pragma unroll
    for (int cg = 0; cg < 4; ++cg) {
      f16x8 bh = *(const f16x8*)(pbh + (long)cg * 16 * K_ + kb * 32);
      f16x8 bl = *(const f16x8*)(pbl + (long)cg * 16 * K_ + kb * 32);
      accA[cg] = MFMA16(ah, bh, accA[cg]);
      accB[cg] = MFMA16(ah, bl, accB[cg]);
      accB[cg] = MFMA16(al, bh, accB[cg]);
    }
  }
  const long ybase = ((long)m0 + wid * 16) * (long)COUT + coutb;
#pragma unroll
  for (int cg = 0; cg < 4; ++cg)
#pragma unroll
    for (int j = 0; j < 4; ++j) {
      int r = lk * 4 + j;
      float y = accA[cg][j] + accB[cg][j] * kDS;
      long idx = ybase + (long)r * COUT + cg * 16 + l15;
      if (F32OUT) Yf[idx] = y;
      else        split2(y, Yh + idx, Yl + idx);
    }
}

// ---------------- attention on interleaved QKV [tok][768] pairs ------------
__global__ __launch_bounds__(256) void attn_kernel(
    f16* __restrict__ QKVh, f16* __restrict__ QKVl) {
  __shared__ float sq[4][16][33];
  __shared__ float sk[4][16][33];
  __shared__ float sv[4][16][33];
  __shared__ float ss[4][16][17];
  const int wid = threadIdx.x >> 6, lane = threadIdx.x & 63;
  const int p = blockIdx.x * 4 + wid;
  const int cs = p >> 12;
  const int loc = p & 4095;
  const int nh = loc >> 9;
  const int vox = loc & 511;
  const int srow = lane >> 2;
  const int dp = (lane & 3) * 8;
  const long sbase = (long)cs * 6291456;
  const long base = sbase + ((long)(srow * 512 + vox)) * 768 + nh * 32 + dp;

  {
    f16x8 qh = *(const f16x8*)(QKVh + base);
    f16x8 ql = *(const f16x8*)(QKVl + base);
    f16x8 kh = *(const f16x8*)(QKVh + base + 256);
    f16x8 kl = *(const f16x8*)(QKVl + base + 256);
    f16x8 vh = *(const f16x8*)(QKVh + base + 512);
    f16x8 vl = *(const f16x8*)(QKVl + base + 512);
#pragma unroll
    for (int j = 0; j < 8; ++j) {
      sq[wid][srow][dp + j] = rec2(qh[j], ql[j]);
      sk[wid][srow][dp + j] = rec2(kh[j], kl[j]);
      sv[wid][srow][dp + j] = rec2(vh[j], vl[j]);
    }
  }
  __syncthreads();
#pragma unroll
  for (int pp = 0; pp < 4; ++pp) {
    int pr = lane * 4 + pp;
    int qi = pr >> 4, kt = pr & 15;
    float s = 0.f;
#pragma unroll
    for (int d = 0; d < 32; ++d) s += sq[wid][qi][d] * sk[wid][kt][d];
    bool allowed = (kt < 8) || (kt <= qi);
    ss[wid][qi][kt] = allowed ? s * 0.17677669529663687f : -1e30f;
  }
  __syncthreads();
  if (lane < 16) {
    float m = -1e30f;
#pragma unroll
    for (int t = 0; t < 16; ++t) m = fmaxf(m, ss[wid][lane][t]);
    float ex[16];
    float sum = 0.f;
#pragma unroll
    for (int t = 0; t < 16; ++t) { ex[t] = expf(ss[wid][lane][t] - m); sum += ex[t]; }
    float inv = 1.0f / sum;
#pragma unroll
    for (int t = 0; t < 16; ++t) ss[wid][lane][t] = ex[t] * inv;
  }
  __syncthreads();
  float o[8] = {0, 0, 0, 0, 0, 0, 0, 0};
#pragma unroll
  for (int t = 0; t < 16; ++t) {
    float a = ss[wid][srow][t];
#pragma unroll
    for (int j = 0; j < 8; ++j) o[j] += a * sv[wid][t][dp + j];
  }
#pragma unroll
  for (int j = 0; j < 8; ++j) split2(o[j], QKVh + base + j, QKVl + base + j);
}

// ---------------- LayerNorm in place on H pair -----------------------------
__global__ __launch_bounds__(256) void ln_kernel(
    f16* __restrict__ Hh, f16* __restrict__ Hl,
    const float* __restrict__ gam, const float* __restrict__ bet) {
  const int wid = threadIdx.x >> 6, lane = threadIdx.x & 63;
  const long tok = (long)blockIdx.x * 4 + wid;
  const long base = tok * 256 + lane * 4;
  f16x4 hh = *(const f16x4*)(Hh + base);
  f16x4 hl = *(const f16x4*)(Hl + base);
  float v0 = rec2(hh[0], hl[0]), v1 = rec2(hh[1], hl[1]);
  float v2 = rec2(hh[2], hl[2]), v3 = rec2(hh[3], hl[3]);
  float mu = wave_sum_f(v0 + v1 + v2 + v3) * (1.0f / 256.0f);
  float d0 = v0 - mu, d1 = v1 - mu, d2 = v2 - mu, d3 = v3 - mu;
  float var = wave_sum_f(d0 * d0 + d1 * d1 + d2 * d2 + d3 * d3) * (1.0f / 256.0f);
  float rs = rsqrtf(var + 1e-5f);
  float4 gv = *(const float4*)(gam + lane * 4);
  float4 bv = *(const float4*)(bet + lane * 4);
  float y0 = d0 * rs * gv.x + bv.x, y1 = d1 * rs * gv.y + bv.y;
  float y2 = d2 * rs * gv.z + bv.z, y3 = d3 * rs * gv.w + bv.w;
  f16x4 oh, ol;
  f16 a, b2;
  split2(y0, &a, &b2); oh[0] = a; ol[0] = b2;
  split2(y1, &a, &b2); oh[1] = a; ol[1] = b2;
  split2(y2, &a, &b2); oh[2] = a; ol[2] = b2;
  split2(y3, &a, &b2); oh[3] = a; ol[3] = b2;
  *(f16x4*)(Hh + base) = oh;
  *(f16x4*)(Hl + base) = ol;
}

// ---------------- classifier LN + GELU in-place (pairs) --------------------
__global__ __launch_bounds__(256) void ln_gelu_kernel(
    f16* __restrict__ Zh, f16* __restrict__ Zl,
    const float* __restrict__ gam, const float* __restrict__ bet) {
  const int wid = threadIdx.x >> 6, lane = threadIdx.x & 63;
  const long tok = (long)blockIdx.x * 4 + wid;
  const long base = tok * 256 + lane * 4;
  f16x4 hh = *(const f16x4*)(Zh + base);
  f16x4 hl = *(const f16x4*)(Zl + base);
  float v0 = rec2(hh[0], hl[0]), v1 = rec2(hh[1], hl[1]);
  float v2 = rec2(hh[2], hl[2]), v3 = rec2(hh[3], hl[3]);
  float mu = wave_sum_f(v0 + v1 + v2 + v3) * (1.0f / 256.0f);
  float d0 = v0 - mu, d1 = v1 - mu, d2 = v2 - mu, d3 = v3 - mu;
  float var = wave_sum_f(d0 * d0 + d1 * d1 + d2 * d2 + d3 * d3) * (1.0f / 256.0f);
  float rs = rsqrtf(var + 1e-5f);
  float4 gv = *(const float4*)(gam + lane * 4);
  float4 bv = *(const float4*)(bet + lane * 4);
  float y0 = gelu_exact(d0 * rs * gv.x + bv.x);
  float y1 = gelu_exact(d1 * rs * gv.y + bv.y);
  float y2 = gelu_exact(d2 * rs * gv.z + bv.z);
  float y3 = gelu_exact(d3 * rs * gv.w + bv.w);
  f16x4 oh, ol;
  f16 a, b2;
  split2(y0, &a, &b2); oh[0] = a; ol[0] = b2;
  split2(y1, &a, &b2); oh[1] = a; ol[1] = b2;
  split2(y2, &a, &b2); oh[2] = a; ol[2] = b2;
  split2(y3, &a, &b2); oh[3] = a; ol[3] = b2;
  *(f16x4*)(Zh + base) = oh;
  *(f16x4*)(Zl + base) = ol;
}

// ---------------- classifier token gather (pair copy) ----------------------
__global__ __launch_bounds__(256) void gather_kernel(
    const f16* __restrict__ Hh, const f16* __restrict__ Hl, int n,
    f16* __restrict__ Xh, f16* __restrict__ Xl) {
  const int tc = blockIdx.x;       // (s2*3+c)*512+vox
  const int e = threadIdx.x;
  const int s2 = tc / 1536;
  int r = tc - s2 * 1536;
  const int c = r >> 9;
  const int vox = r & 511;
  const int g = n * 3 + c;
  const int s = 7 + s2;
  const long src = ((long)(g * 16 + s) * 512 + vox) * 256 + e;
  const long dst = (long)tc * 256 + e;
  Xh[dst] = Hh[src];
  Xl[dst] = Hl[src];
}

// ---------------- score transpose: Z2[t][k] -> out[k][t] (per n) -----------
__global__ __launch_bounds__(256) void transpose_kernel(
    const float* __restrict__ Z2, float* __restrict__ out) {
  __shared__ float tile[32][33];
  const int t0 = blockIdx.x * 32;
  const int k0 = blockIdx.y * 32;
  const int tx = threadIdx.x & 31;
  const int ty = threadIdx.x >> 5;
#pragma unroll
  for (int i = 0; i < 32; i += 8)
    tile[ty + i][tx] = Z2[((long)(t0 + ty + i)) * 512 + k0 + tx];
  __syncthreads();
#pragma unroll
  for (int i = 0; i < 32; i += 8)
    out[((long)(k0 + ty + i)) * 13824 + t0 + tx] = tile[tx][ty + i];
}

// ---------------- loss + pred (per n chunk) --------------------------------
__global__ __launch_bounds__(256) void loss_pred_kernel(
    const float* __restrict__ Z2, const int* __restrict__ ncode,
    float* __restrict__ pred, float* __restrict__ partial) {
  __shared__ float sh[4];
  const int wid = threadIdx.x >> 6, lane = threadIdx.x & 63;
  const int tok = blockIdx.x * 4 + wid;
  const float* row = Z2 + (long)tok * 512;
  float4 a = *(const float4*)(row + lane * 8);
  float4 b = *(const float4*)(row + lane * 8 + 4);
  float vals[8] = {a.x, a.y, a.z, a.w, b.x, b.y, b.z, b.w};
  float mx = vals[0];
  int mi = lane * 8;
#pragma unroll
  for (int j = 1; j < 8; ++j)
    if (vals[j] > mx) { mx = vals[j]; mi = lane * 8 + j; }
#pragma unroll
  for (int m = 1; m < 64; m <<= 1) {
    float ox = __shfl_xor(mx, m);
    int oi = __shfl_xor(mi, m);
    if (ox > mx || (ox == mx && oi < mi)) { mx = ox; mi = oi; }
  }
  float se = 0.f;
#pragma unroll
  for (int j = 0; j < 8; ++j) se += expf(vals[j] - mx);
  se = wave_sum_f(se);
  if (lane == 0) {
    int tgt = ncode[tok];
    float nll = mx + logf(se) - row[tgt];
    pred[tok] = (float)mi;
    sh[wid] = nll;
  }
  __syncthreads();
  if (threadIdx.x == 0) partial[blockIdx.x] = sh[0] + sh[1] + sh[2] + sh[3];
}

__global__ __launch_bounds__(256) void loss_final_kernel(
    const float* __restrict__ partial, float* __restrict__ out) {
  __shared__ float sh[4];
  float s = 0.f;
  for (int i = threadIdx.x; i < 6912; i += 256) s += partial[i];
  s = wave_sum_f(s);
  if ((threadIdx.x & 63) == 0) sh[threadIdx.x >> 6] = s;
  __syncthreads();
  if (threadIdx.x == 0) out[0] = (sh[0] + sh[1] + sh[2] + sh[3]) * (1.0f / 27648.0f);
}

// ---------------- sentinel fill --------------------------------------------
__global__ __launch_bounds__(256) void fill_kernel(float* __restrict__ p, long n, float v) {
  long i = (long)blockIdx.x * 256 + threadIdx.x;
  if (i < n) p[i] = v;
}

// ===========================================================================
extern "C" void kernel_launch(void* const* d_in, const int* in_sizes, int n_in,
                              void* d_out, int out_size, void* d_ws, size_t ws_size,
                              hipStream_t stream) {
  const int* code   = (const int*)d_in[0];
  const int* ncode  = (const int*)d_in[1];
  const float* emb  = (const float*)d_in[2];
  const float* pos  = (const float*)d_in[3];
  const float* Wq   = (const float*)d_in[4];
  const float* bq   = (const float*)d_in[5];
  const float* Wk   = (const float*)d_in[6];
  const float* bk   = (const float*)d_in[7];
  const float* Wv   = (const float*)d_in[8];
  const float* bv   = (const float*)d_in[9];
  const float* Wo   = (const float*)d_in[10];
  const float* bo   = (const float*)d_in[11];
  const float* ln1g = (const float*)d_in[12];
  const float* ln1b = (const float*)d_in[13];
  const float* ln2g = (const float*)d_in[14];
  const float* ln2b = (const float*)d_in[15];
  const float* Wc1  = (const float*)d_in[16];
  const float* bc1  = (const float*)d_in[17];
  const float* Wc2  = (const float*)d_in[18];
  const float* bc2  = (const float*)d_in[19];
  const float* cW1  = (const float*)d_in[20];
  const float* cb1  = (const float*)d_in[21];
  const float* clng = (const float*)d_in[22];
  const float* clnb = (const float*)d_in[23];
  const float* cW2  = (const float*)d_in[24];
  const float* cb2  = (const float*)d_in[25];
  float* out = (float*)d_out;
  (void)in_sizes; (void)n_in; (void)out_size;

  // sizes (f16 units)
  const long WSLOT = 5308416;    // 27*768*256 (max per-conv weight, QKV fused)
  const long HSL   = 2097152;    // per-slice H per comp
  const long QSL   = 6291456;    // per-slice QKV interleaved per comp
  const long T1SL  = 4194304;    // per-slice T1 per comp
  const long CLMIN = 21233664;   // classifier slab minimum

  auto needf = [&](int ns) -> size_t {
    long slab = (long)ns * 2 * QSL;
    if (slab < CLMIN) slab = CLMIN;
    return (size_t)(2 * WSLOT + 2 * 12582912L + slab) * 2 + 6912 * 4 + 768 * 4 + 4096;
  };
  int NS = 0;
  if      (ws_size >= needf(6)) NS = 6;
  else if (ws_size >= needf(3)) NS = 3;
  else if (ws_size >= needf(2)) NS = 2;
  else if (ws_size >= needf(1)) NS = 1;
  if (NS == 0) {
    fill_kernel<<<dim3(109), 256, 0, stream>>>(out + kSC, 27649, -1.0f);
    return;
  }
  long slab_f16 = (long)NS * 2 * QSL;
  if (slab_f16 < CLMIN) slab_f16 = CLMIN;

  f16* wh = (f16*)d_ws;
  f16* wl = wh + WSLOT;
  f16* Hh = wl + WSLOT;
  f16* Hl = Hh + 12582912;
  f16* S  = Hl + 12582912;
  float* partial = (float*)(S + slab_f16);
  float* bcat = partial + 6912;

  const size_t WQKVO = 27u * 256 * 256;
  const size_t WC1SZ = 27u * 256 * 512;
  const size_t WC2SZ = 27u * 512 * 256;

  embed_kernel<<<dim3(49152), 256, 0, stream>>>(code, ncode, emb, pos, Hh, Hl);

  const int nchunk = 6 / NS;
  f16* qkvh = S;
  f16* qkvl = S + (long)NS * QSL;
  f16* t1h  = S;
  f16* t1l  = S + (long)NS * T1SL;

  for (int l = 0; l < 2; ++l) {
    const float* wq = Wq + (size_t)l * WQKVO;
    const float* wk = Wk + (size_t)l * WQKVO;
    const float* wv = Wv + (size_t)l * WQKVO;
    const float* wo = Wo + (size_t)l * WQKVO;
    const float* wc1 = Wc1 + (size_t)l * WC1SZ;
    const float* wc2 = Wc2 + (size_t)l * WC2SZ;
    bpack_kernel<<<dim3(3), 256, 0, stream>>>(bq + l * 256, bk + l * 256, bv + l * 256, bcat);
    for (int ch = 0; ch < nchunk; ++ch) {
      f16* Xh = Hh + (long)ch * NS * HSL;
      f16* Xl = Hl + (long)ch * NS * HSL;
      // fused QKV conv
      wsplit_kernel<<<dim3(6912), 256, 0, stream>>>(wq, wh, wl, 27, 256, 256, 768, 0);
      wsplit_kernel<<<dim3(6912), 256, 0, stream>>>(wk, wh, wl, 27, 256, 256, 768, 256);
      wsplit_kernel<<<dim3(6912), 256, 0, stream>>>(wv, wh, wl, 27, 256, 256, 768, 512);
      conv13_kernel<256, 768, 0, 0><<<dim3(64 * 6 * NS), 256, 0, stream>>>(
          Xh, Xl, HSL, 256, wh, wl, bcat, qkvh, qkvl, QSL, 768, NS);
      attn_kernel<<<dim3(NS * 1024), 256, 0, stream>>>(qkvh, qkvl);
      // O projection with fused residual into H
      wsplit_kernel<<<dim3(6912), 256, 0, stream>>>(wo, wh, wl, 27, 256, 256, 256, 0);
      conv13_kernel<256, 256, 0, 1><<<dim3(64 * 2 * NS), 256, 0, stream>>>(
          qkvh, qkvl, QSL, 768, wh, wl, bo + l * 256, Xh, Xl, HSL, 256, NS);
      ln_kernel<<<dim3(2048 * NS), 256, 0, stream>>>(Xh, Xl, ln1g + l * 256, ln1b + l * 256);
      // FFN1 with fused gelu
      wsplit_kernel<<<dim3(13824), 256, 0, stream>>>(wc1, wh, wl, 27, 256, 512, 512, 0);
      conv13_kernel<256, 512, 1, 0><<<dim3(64 * 4 * NS), 256, 0, stream>>>(
          Xh, Xl, HSL, 256, wh, wl, bc1 + l * 512, t1h, t1l, T1SL, 512, NS);
      // FFN2 with fused residual
      wsplit_kernel<<<dim3(13824), 256, 0, stream>>>(wc2, wh, wl, 27, 512, 256, 256, 0);
      conv13_kernel<512, 256, 0, 1><<<dim3(64 * 2 * NS), 256, 0, stream>>>(
          t1h, t1l, T1SL, 512, wh, wl, bc2 + l * 256, Xh, Xl, HSL, 256, NS);
      ln_kernel<<<dim3(2048 * NS), 256, 0, stream>>>(Xh, Xl, ln2g + l * 256, ln2b + l * 256);
    }
  }

  // ---- classifier, chunked by n ----
  for (int n = 0; n < 2; ++n) {
    f16* Z1h = S;
    f16* Z1l = S + 3538944;
    f16* Xch = S + 7077888;
    f16* Xcl = S + 10616832;
    float* Z2 = (float*)(S + 7077888);   // overwrites Xc (dead after gemm1)
    gather_kernel<<<dim3(13824), 256, 0, stream>>>(Hh, Hl, n, Xch, Xcl);
    wsplit_kernel<<<dim3(256), 256, 0, stream>>>(cW1, wh, wl, 1, 256, 256, 256, 0);
    gemm_kernel<256, 256, false><<<dim3(216, 4), 256, 0, stream>>>(Xch, Xcl, wh, wl, cb1, Z1h, Z1l, nullptr);
    ln_gelu_kernel<<<dim3(3456), 256, 0, stream>>>(Z1h, Z1l, clng, clnb);
    wsplit_kernel<<<dim3(512), 256, 0, stream>>>(cW2, wh, wl, 1, 256, 512, 512, 0);
    gemm_kernel<256, 512, true><<<dim3(216, 8), 256, 0, stream>>>(Z1h, Z1l, wh, wl, cb2, nullptr, nullptr, Z2);
    transpose_kernel<<<dim3(432, 16), 256, 0, stream>>>(Z2, out + (long)n * 512 * 13824);
    loss_pred_kernel<<<dim3(3456), 256, 0, stream>>>(Z2, ncode + n * 13824,
                                                     out + kSC + 1 + n * 13824, partial + n * 3456);
  }
  loss_final_kernel<<<dim3(1), 256, 0, stream>>>(partial, out + kSC);
}

// Round 14
// 7447.034 us; speedup vs baseline: 7.5044x; 7.5044x over previous
//
#include <hip/hip_runtime.h>

// ---------------------------------------------------------------------------
// Transformer_90426241450054 — MI355X (round 14, final tuning)
// Numerics: proven 3-mult split-f16 pairs (x ~= hi + lo*2^-11, fp32 parity).
// conv14 = R5's conv4 (fastest proven conv: 128x128 tile, 64 KB LDS,
// global_load_lds staging with source-side XOR swizzle, one barrier/tap,
// 2 blocks/CU) + wave-uniform tap-skip + setprio around MFMA cluster.
// ---------------------------------------------------------------------------

typedef _Float16 f16;
typedef __attribute__((ext_vector_type(8))) _Float16 f16x8;
typedef __attribute__((ext_vector_type(4))) _Float16 f16x4;
typedef __attribute__((ext_vector_type(4))) float f32x4;

static constexpr long kSC = 14155776;               // score elems = 2*512*13824
static constexpr float kDS = 4.8828125e-4f;         // 2^-11

#define MFMA16(a, b, c) __builtin_amdgcn_mfma_f32_16x16x32_f16((a), (b), (c), 0, 0, 0)

__device__ __forceinline__ void gl16(const void* g, void* l) {
  __builtin_amdgcn_global_load_lds((const __attribute__((address_space(1))) void*)g,
                                   (__attribute__((address_space(3))) void*)l,
                                   16, 0, 0);
}

__device__ __forceinline__ float wave_sum_f(float x) {
#pragma unroll
  for (int m = 32; m; m >>= 1) x += __shfl_xor(x, m);
  return x;
}

__device__ __forceinline__ void split2(float x, f16* h, f16* l) {
  f16 hh = (f16)x;
  *h = hh;
  *l = (f16)((x - (float)hh) * 2048.0f);
}

__device__ __forceinline__ float rec2(f16 h, f16 l) {
  return (float)h + (float)l * kDS;
}

__device__ __forceinline__ float gelu_exact(float x) {
  return 0.5f * x * (1.0f + erff(x * 0.70710678118654752f));
}

// ---------------- weight split: [G][Ci][Co] f32 -> [G][CoTot][Ci] pair ------
__global__ __launch_bounds__(256) void wsplit_kernel(
    const float* __restrict__ src, f16* __restrict__ hi, f16* __restrict__ lo,
    int G, int Ci, int Co, int CoTot, int co0) {
  long n = (long)G * Ci * Co;
  long i = (long)blockIdx.x * 256 + threadIdx.x;
  if (i >= n) return;
  int co = (int)(i % Co);
  long t = i / Co;
  int ci = (int)(t % Ci);
  int g  = (int)(t / Ci);
  float x = src[i];
  long o = ((long)g * CoTot + co0 + co) * Ci + ci;
  split2(x, hi + o, lo + o);
}

// ---------------- bias concat (q,k,v -> 768) -------------------------------
__global__ __launch_bounds__(256) void bpack_kernel(
    const float* __restrict__ bq, const float* __restrict__ bk,
    const float* __restrict__ bv, float* __restrict__ dst) {
  int i = blockIdx.x * 256 + threadIdx.x;
  if (i < 256) dst[i] = bq[i];
  else if (i < 512) dst[i] = bk[i - 256];
  else if (i < 768) dst[i] = bv[i - 512];
}

// ---------------- embedding + pos -> H pair --------------------------------
__global__ __launch_bounds__(256) void embed_kernel(
    const int* __restrict__ code, const int* __restrict__ ncode,
    const float* __restrict__ emb, const float* __restrict__ pos,
    f16* __restrict__ Hh, f16* __restrict__ Hl) {
  int tok = blockIdx.x;            // g*8192 + s*512 + vox
  int e = threadIdx.x;
  int g = tok >> 13;
  int rem = tok & 8191;
  int s = rem >> 9;
  int vox = rem & 511;
  int n = g / 3, c = g - 3 * n;
  int idx;
  if (s < 8) idx = code[((n * 8 + s) * 3 + c) * 512 + vox];
  else       idx = ncode[((n * 9 + (s - 8)) * 3 + c) * 512 + vox];
  float val = emb[idx * 256 + e] + pos[s * 256 + e];
  long o = (long)tok * 256 + e;
  split2(val, Hh + o, Hl + o);
}

// ---------------- conv3d 3x3x3 SAME, v14 (= v4 + tap-skip + setprio) -------
template <int CIN, int COUTT, int ACT, int RESID>
__global__ __launch_bounds__(256, 2) void conv14_kernel(
    const f16* __restrict__ Xh, const f16* __restrict__ Xl, long xz_s, int xr,
    const f16* __restrict__ Wh, const f16* __restrict__ Wl,
    const float* __restrict__ bias,
    f16* __restrict__ Yh, f16* __restrict__ Yl, long yz_s, int yr, int nz) {
  constexpr int KB = CIN / 32;
  constexpr int NY = COUTT / 128;
  __shared__ __align__(16) f16 lsAll[32768];   // 64 KB
  // f16 offsets: A0 [0,8192) A1 [8192,16384)
  //              B: 16384 + buf*8192 + comp*4096 + row*32 + slot*8

  const int nwg = 64 * NY * nz;
  const int q = nwg >> 3;
  const int bid = blockIdx.x;
  const int wg = (bid & 7) * q + (bid >> 3);
  const int y = wg / (64 * nz);
  const int rem = wg - y * (64 * nz);
  const int z = rem >> 6;
  const int mt = rem & 63;
  const int img = mt >> 2, up = mt & 3;
  const int u0 = up * 2;
  const int coutb0 = y * 128;

  const int tid = threadIdx.x;
  const int wid = tid >> 6, lane = tid & 63;
  const int wm = wid >> 1, wn = wid & 1;
  const int l15 = lane & 15, lk = lane >> 4;

  const long xz = (long)z * xz_s;
  const long yz = (long)z * yz_s;

  f32x4 aA[4][4], aB[4][4];
#pragma unroll
  for (int mf = 0; mf < 4; ++mf)
#pragma unroll
    for (int nf = 0; nf < 4; ++nf) {
      float bv = bias[coutb0 + wn * 64 + nf * 16 + l15];
      aA[mf][nf] = (f32x4){bv, bv, bv, bv};
      aB[mf][nf] = (f32x4){0.f, 0.f, 0.f, 0.f};
    }

  const int swrow = tid >> 2;           // staging row
  const int sswz = (tid & 3) ^ ((tid >> 3) & 3);  // staged col swizzle

  auto stageA = [&](int kb) {
#pragma unroll
    for (int j = 0; j < 4; ++j) {
      const int uu = u0 - 1 + j;
      if (uu < 0 || uu >= 8) continue;  // block-uniform
      const long g = xz + ((long)(img * 512 + uu * 64 + swrow)) * (long)xr
                     + kb * 32 + sswz * 8;
      gl16(Xh + g, &lsAll[j * 2048 + tid * 8]);
      gl16(Xl + g, &lsAll[8192 + j * 2048 + tid * 8]);
    }
  };
  auto stageB = [&](int o, int kb, int buf) {
    const int wb = 16384 + buf * 8192;
#pragma unroll
    for (int i = 0; i < 2; ++i) {
      const long g = ((long)o * COUTT + coutb0 + i * 64 + swrow) * (long)CIN
                     + kb * 32 + sswz * 8;
      gl16(Wh + g, &lsAll[wb + i * 2048 + tid * 8]);
      gl16(Wl + g, &lsAll[wb + 4096 + i * 2048 + tid * 8]);
    }
  };
  auto compute = [&](int o, int buf) {
    const int du = o / 9 - 1, dv = (o / 3) % 3 - 1, dw = o % 3 - 1;
    const int gu = u0 + wm + du;
    if ((unsigned)gu >= 8u) return;     // wave-uniform tap skip (barrier outside)
    const int p = wm + 1 + du;
    const int wb = 16384 + buf * 8192;
    f16x8 bh[4], bl[4];
#pragma unroll
    for (int nf = 0; nf < 4; ++nf) {
      const int rb = wn * 64 + nf * 16 + l15;
      const int sw = lk ^ ((rb >> 1) & 3);
      bh[nf] = *(const f16x8*)&lsAll[wb + rb * 32 + sw * 8];
      bl[nf] = *(const f16x8*)&lsAll[wb + 4096 + rb * 32 + sw * 8];
    }
    __builtin_amdgcn_s_setprio(1);
#pragma unroll
    for (int mf = 0; mf < 4; ++mf) {
      const int vrow = mf * 16 + l15;
      const int vv = (vrow >> 3) + dv, ww = (vrow & 7) + dw;
      const bool ok = ((unsigned)vv < 8u) && ((unsigned)ww < 8u);
      f16x8 ah = {0, 0, 0, 0, 0, 0, 0, 0};
      f16x8 al = {0, 0, 0, 0, 0, 0, 0, 0};
      if (ok) {
        const int lrow = p * 64 + vv * 8 + ww;
        const int sw = lk ^ ((lrow >> 1) & 3);
        ah = *(const f16x8*)&lsAll[lrow * 32 + sw * 8];
        al = *(const f16x8*)&lsAll[8192 + lrow * 32 + sw * 8];
      }
#pragma unroll
      for (int nf = 0; nf < 4; ++nf) {
        aA[mf][nf] = MFMA16(ah, bh[nf], aA[mf][nf]);
        aB[mf][nf] = MFMA16(ah, bl[nf], aB[mf][nf]);
        aB[mf][nf] = MFMA16(al, bh[nf], aB[mf][nf]);
      }
    }
    __builtin_amdgcn_s_setprio(0);
  };

  // prologue
  stageA(0);
  stageB(0, 0, 0);
  __syncthreads();

  int cur = 0;
#pragma unroll 1
  for (int kb = 0; kb < KB; ++kb) {
#pragma unroll 1
    for (int o = 0; o < 27; ++o) {
      if (o < 26)           stageB(o + 1, kb, cur ^ 1);
      else if (kb + 1 < KB) stageB(0, kb + 1, cur ^ 1);
      compute(o, cur);
      __syncthreads();
      cur ^= 1;
    }
    if (kb + 1 < KB) {
      stageA(kb + 1);
      __syncthreads();
    }
  }

  // epilogue: two row-half passes through LDS (padded stride, conflict-free)
  float* sY = (float*)lsAll;            // [64][132]
#pragma unroll 1
  for (int rh = 0; rh < 2; ++rh) {
    if (wm == rh) {
#pragma unroll
      for (int mf = 0; mf < 4; ++mf)
#pragma unroll
        for (int nf = 0; nf < 4; ++nf)
#pragma unroll
          for (int j = 0; j < 4; ++j) {
            const int row = mf * 16 + lk * 4 + j;
            const int col = wn * 64 + nf * 16 + l15;
            sY[row * 132 + col] = aA[mf][nf][j] + aB[mf][nf][j] * kDS;
          }
    }
    __syncthreads();
#pragma unroll
    for (int it = 0; it < 2; ++it) {
      const int row = it * 32 + (tid >> 3);
      const int c0 = (tid & 7) * 16;
      const long grow = (long)img * 512 + (u0 + rh) * 64 + row;
      const long gidx = yz + grow * (long)yr + coutb0 + c0;
      float yv[16];
#pragma unroll
      for (int i2 = 0; i2 < 16; ++i2) yv[i2] = sY[row * 132 + c0 + i2];
      if (ACT) {
#pragma unroll
        for (int i2 = 0; i2 < 16; ++i2) yv[i2] = gelu_exact(yv[i2]);
      }
      if (RESID) {
        f16x8 r0h = *(const f16x8*)&Yh[gidx];
        f16x8 r1h = *(const f16x8*)&Yh[gidx + 8];
        f16x8 r0l = *(const f16x8*)&Yl[gidx];
        f16x8 r1l = *(const f16x8*)&Yl[gidx + 8];
#pragma unroll
        for (int i2 = 0; i2 < 8; ++i2) {
          yv[i2] += rec2(r0h[i2], r0l[i2]);
          yv[8 + i2] += rec2(r1h[i2], r1l[i2]);
        }
      }
      f16x8 h0, h1, l0, l1;
#pragma unroll
      for (int i2 = 0; i2 < 8; ++i2) {
        f16 a, b;
        split2(yv[i2], &a, &b); h0[i2] = a; l0[i2] = b;
        split2(yv[8 + i2], &a, &b); h1[i2] = a; l1[i2] = b;
      }
      *(f16x8*)&Yh[gidx] = h0;
      *(f16x8*)&Yh[gidx + 8] = h1;
      *(f16x8*)&Yl[gidx] = l0;
      *(f16x8*)&Yl[gidx + 8] = l1;
    }
    __syncthreads();
  }
}

// ---------------- plain GEMM (classifier), pair in, pair or f32 out --------
template <int K_, int COUT, bool F32OUT>
__global__ __launch_bounds__(256) void gemm_kernel(
    const f16* __restrict__ Xh, const f16* __restrict__ Xl,
    const f16* __restrict__ Wh, const f16* __restrict__ Wl,
    const float* __restrict__ bias,
    f16* __restrict__ Yh, f16* __restrict__ Yl, float* __restrict__ Yf) {
  const int m0 = blockIdx.x * 64;
  const int coutb = blockIdx.y * 64;
  const int tid = threadIdx.x;
  const int wid = tid >> 6, lane = tid & 63;
  const int l15 = lane & 15, lk = lane >> 4;
  const int arow = m0 + wid * 16 + l15;

  f32x4 accA[4], accB[4];
#pragma unroll
  for (int cg = 0; cg < 4; ++cg) {
    float bv = bias[coutb + cg * 16 + l15];
    accA[cg] = (f32x4){bv, bv, bv, bv};
    accB[cg] = (f32x4){0.f, 0.f, 0.f, 0.f};
  }
  const f16* pah = Xh + (long)arow * K_ + lk * 8;
  const f16* pal = Xl + (long)arow * K_ + lk * 8;
  const f16* pbh = Wh + ((long)coutb + l15) * K_ + lk * 8;
  const f16* pbl = Wl + ((long)coutb + l15) * K_ + lk * 8;
#pragma unroll 2
  for (int kb = 0; kb < K_ / 32; ++kb) {
    f16x8 ah = *(const f16x8*)(pah + kb * 32);
    f16x8 al = *(const f16x8*)(pal + kb * 32);
#pragma unroll
    for (int cg = 0; cg < 4; ++cg) {
      f16x8 bh = *(const f16x8*)(pbh + (long)cg * 16 * K_ + kb * 32);
      f16x8 bl = *(const f16x8*)(pbl + (long)cg * 16 * K_ + kb * 32);
      accA[cg] = MFMA16(ah, bh, accA[cg]);
      accB[cg] = MFMA16(ah, bl, accB[cg]);
      accB[cg] = MFMA16(al, bh, accB[cg]);
    }
  }
  const long ybase = ((long)m0 + wid * 16) * (long)COUT + coutb;
#pragma unroll
  for (int cg = 0; cg < 4; ++cg)
#pragma unroll
    for (int j = 0; j < 4; ++j) {
      int r = lk * 4 + j;
      float y = accA[cg][j] + accB[cg][j] * kDS;
      long idx = ybase + (long)r * COUT + cg * 16 + l15;
      if (F32OUT) Yf[idx] = y;
      else        split2(y, Yh + idx, Yl + idx);
    }
}

// ---------------- attention on interleaved QKV [tok][768] pairs ------------
__global__ __launch_bounds__(256) void attn_kernel(
    f16* __restrict__ QKVh, f16* __restrict__ QKVl) {
  __shared__ float sq[4][16][33];
  __shared__ float sk[4][16][33];
  __shared__ float sv[4][16][33];
  __shared__ float ss[4][16][17];
  const int wid = threadIdx.x >> 6, lane = threadIdx.x & 63;
  const int p = blockIdx.x * 4 + wid;
  const int cs = p >> 12;
  const int loc = p & 4095;
  const int nh = loc >> 9;
  const int vox = loc & 511;
  const int srow = lane >> 2;
  const int dp = (lane & 3) * 8;
  const long sbase = (long)cs * 6291456;
  const long base = sbase + ((long)(srow * 512 + vox)) * 768 + nh * 32 + dp;

  {
    f16x8 qh = *(const f16x8*)(QKVh + base);
    f16x8 ql = *(const f16x8*)(QKVl + base);
    f16x8 kh = *(const f16x8*)(QKVh + base + 256);
    f16x8 kl = *(const f16x8*)(QKVl + base + 256);
    f16x8 vh = *(const f16x8*)(QKVh + base + 512);
    f16x8 vl = *(const f16x8*)(QKVl + base + 512);
#pragma unroll
    for (int j = 0; j < 8; ++j) {
      sq[wid][srow][dp + j] = rec2(qh[j], ql[j]);
      sk[wid][srow][dp + j] = rec2(kh[j], kl[j]);
      sv[wid][srow][dp + j] = rec2(vh[j], vl[j]);
    }
  }
  __syncthreads();
#pragma unroll
  for (int pp = 0; pp < 4; ++pp) {
    int pr = lane * 4 + pp;
    int qi = pr >> 4, kt = pr & 15;
    float s = 0.f;
#pragma unroll
    for (int d = 0; d < 32; ++d) s += sq[wid][qi][d] * sk[wid][kt][d];
    bool allowed = (kt < 8) || (kt <= qi);
    ss[wid][qi][kt] = allowed ? s * 0.17677669529663687f : -1e30f;
  }
  __syncthreads();
  if (lane < 16) {
    float m = -1e30f;
#pragma unroll
    for (int t = 0; t < 16; ++t) m = fmaxf(m, ss[wid][lane][t]);
    float ex[16];
    float sum = 0.f;
#pragma unroll
    for (int t = 0; t < 16; ++t) { ex[t] = expf(ss[wid][lane][t] - m); sum += ex[t]; }
    float inv = 1.0f / sum;
#pragma unroll
    for (int t = 0; t < 16; ++t) ss[wid][lane][t] = ex[t] * inv;
  }
  __syncthreads();
  float o[8] = {0, 0, 0, 0, 0, 0, 0, 0};
#pragma unroll
  for (int t = 0; t < 16; ++t) {
    float a = ss[wid][srow][t];
#pragma unroll
    for (int j = 0; j < 8; ++j) o[j] += a * sv[wid][t][dp + j];
  }
#pragma unroll
  for (int j = 0; j < 8; ++j) split2(o[j], QKVh + base + j, QKVl + base + j);
}

// ---------------- LayerNorm in place on H pair -----------------------------
__global__ __launch_bounds__(256) void ln_kernel(
    f16* __restrict__ Hh, f16* __restrict__ Hl,
    const float* __restrict__ gam, const float* __restrict__ bet) {
  const int wid = threadIdx.x >> 6, lane = threadIdx.x & 63;
  const long tok = (long)blockIdx.x * 4 + wid;
  const long base = tok * 256 + lane * 4;
  f16x4 hh = *(const f16x4*)(Hh + base);
  f16x4 hl = *(const f16x4*)(Hl + base);
  float v0 = rec2(hh[0], hl[0]), v1 = rec2(hh[1], hl[1]);
  float v2 = rec2(hh[2], hl[2]), v3 = rec2(hh[3], hl[3]);
  float mu = wave_sum_f(v0 + v1 + v2 + v3) * (1.0f / 256.0f);
  float d0 = v0 - mu, d1 = v1 - mu, d2 = v2 - mu, d3 = v3 - mu;
  float var = wave_sum_f(d0 * d0 + d1 * d1 + d2 * d2 + d3 * d3) * (1.0f / 256.0f);
  float rs = rsqrtf(var + 1e-5f);
  float4 gv = *(const float4*)(gam + lane * 4);
  float4 bv = *(const float4*)(bet + lane * 4);
  float y0 = d0 * rs * gv.x + bv.x, y1 = d1 * rs * gv.y + bv.y;
  float y2 = d2 * rs * gv.z + bv.z, y3 = d3 * rs * gv.w + bv.w;
  f16x4 oh, ol;
  f16 a, b2;
  split2(y0, &a, &b2); oh[0] = a; ol[0] = b2;
  split2(y1, &a, &b2); oh[1] = a; ol[1] = b2;
  split2(y2, &a, &b2); oh[2] = a; ol[2] = b2;
  split2(y3, &a, &b2); oh[3] = a; ol[3] = b2;
  *(f16x4*)(Hh + base) = oh;
  *(f16x4*)(Hl + base) = ol;
}

// ---------------- classifier LN + GELU in-place (pairs) --------------------
__global__ __launch_bounds__(256) void ln_gelu_kernel(
    f16* __restrict__ Zh, f16* __restrict__ Zl,
    const float* __restrict__ gam, const float* __restrict__ bet) {
  const int wid = threadIdx.x >> 6, lane = threadIdx.x & 63;
  const long tok = (long)blockIdx.x * 4 + wid;
  const long base = tok * 256 + lane * 4;
  f16x4 hh = *(const f16x4*)(Zh + base);
  f16x4 hl = *(const f16x4*)(Zl + base);
  float v0 = rec2(hh[0], hl[0]), v1 = rec2(hh[1], hl[1]);
  float v2 = rec2(hh[2], hl[2]), v3 = rec2(hh[3], hl[3]);
  float mu = wave_sum_f(v0 + v1 + v2 + v3) * (1.0f / 256.0f);
  float d0 = v0 - mu, d1 = v1 - mu, d2 = v2 - mu, d3 = v3 - mu;
  float var = wave_sum_f(d0 * d0 + d1 * d1 + d2 * d2 + d3 * d3) * (1.0f / 256.0f);
  float rs = rsqrtf(var + 1e-5f);
  float4 gv = *(const float4*)(gam + lane * 4);
  float4 bv = *(const float4*)(bet + lane * 4);
  float y0 = gelu_exact(d0 * rs * gv.x + bv.x);
  float y1 = gelu_exact(d1 * rs * gv.y + bv.y);
  float y2 = gelu_exact(d2 * rs * gv.z + bv.z);
  float y3 = gelu_exact(d3 * rs * gv.w + bv.w);
  f16x4 oh, ol;
  f16 a, b2;
  split2(y0, &a, &b2); oh[0] = a; ol[0] = b2;
  split2(y1, &a, &b2); oh[1] = a; ol[1] = b2;
  split2(y2, &a, &b2); oh[2] = a; ol[2] = b2;
  split2(y3, &a, &b2); oh[3] = a; ol[3] = b2;
  *(f16x4*)(Zh + base) = oh;
  *(f16x4*)(Zl + base) = ol;
}

// ---------------- classifier token gather (pair copy) ----------------------
__global__ __launch_bounds__(256) void gather_kernel(
    const f16* __restrict__ Hh, const f16* __restrict__ Hl, int n,
    f16* __restrict__ Xh, f16* __restrict__ Xl) {
  const int tc = blockIdx.x;       // (s2*3+c)*512+vox
  const int e = threadIdx.x;
  const int s2 = tc / 1536;
  int r = tc - s2 * 1536;
  const int c = r >> 9;
  const int vox = r & 511;
  const int g = n * 3 + c;
  const int s = 7 + s2;
  const long src = ((long)(g * 16 + s) * 512 + vox) * 256 + e;
  const long dst = (long)tc * 256 + e;
  Xh[dst] = Hh[src];
  Xl[dst] = Hl[src];
}

// ---------------- score transpose: Z2[t][k] -> out[k][t] (per n) -----------
__global__ __launch_bounds__(256) void transpose_kernel(
    const float* __restrict__ Z2, float* __restrict__ out) {
  __shared__ float tile[32][33];
  const int t0 = blockIdx.x * 32;
  const int k0 = blockIdx.y * 32;
  const int tx = threadIdx.x & 31;
  const int ty = threadIdx.x >> 5;
#pragma unroll
  for (int i = 0; i < 32; i += 8)
    tile[ty + i][tx] = Z2[((long)(t0 + ty + i)) * 512 + k0 + tx];
  __syncthreads();
#pragma unroll
  for (int i = 0; i < 32; i += 8)
    out[((long)(k0 + ty + i)) * 13824 + t0 + tx] = tile[tx][ty + i];
}

// ---------------- loss + pred (per n chunk) --------------------------------
__global__ __launch_bounds__(256) void loss_pred_kernel(
    const float* __restrict__ Z2, const int* __restrict__ ncode,
    float* __restrict__ pred, float* __restrict__ partial) {
  __shared__ float sh[4];
  const int wid = threadIdx.x >> 6, lane = threadIdx.x & 63;
  const int tok = blockIdx.x * 4 + wid;
  const float* row = Z2 + (long)tok * 512;
  float4 a = *(const float4*)(row + lane * 8);
  float4 b = *(const float4*)(row + lane * 8 + 4);
  float vals[8] = {a.x, a.y, a.z, a.w, b.x, b.y, b.z, b.w};
  float mx = vals[0];
  int mi = lane * 8;
#pragma unroll
  for (int j = 1; j < 8; ++j)
    if (vals[j] > mx) { mx = vals[j]; mi = lane * 8 + j; }
#pragma unroll
  for (int m = 1; m < 64; m <<= 1) {
    float ox = __shfl_xor(mx, m);
    int oi = __shfl_xor(mi, m);
    if (ox > mx || (ox == mx && oi < mi)) { mx = ox; mi = oi; }
  }
  float se = 0.f;
#pragma unroll
  for (int j = 0; j < 8; ++j) se += expf(vals[j] - mx);
  se = wave_sum_f(se);
  if (lane == 0) {
    int tgt = ncode[tok];
    float nll = mx + logf(se) - row[tgt];
    pred[tok] = (float)mi;
    sh[wid] = nll;
  }
  __syncthreads();
  if (threadIdx.x == 0) partial[blockIdx.x] = sh[0] + sh[1] + sh[2] + sh[3];
}

__global__ __launch_bounds__(256) void loss_final_kernel(
    const float* __restrict__ partial, float* __restrict__ out) {
  __shared__ float sh[4];
  float s = 0.f;
  for (int i = threadIdx.x; i < 6912; i += 256) s += partial[i];
  s = wave_sum_f(s);
  if ((threadIdx.x & 63) == 0) sh[threadIdx.x >> 6] = s;
  __syncthreads();
  if (threadIdx.x == 0) out[0] = (sh[0] + sh[1] + sh[2] + sh[3]) * (1.0f / 27648.0f);
}

// ---------------- sentinel fill --------------------------------------------
__global__ __launch_bounds__(256) void fill_kernel(float* __restrict__ p, long n, float v) {
  long i = (long)blockIdx.x * 256 + threadIdx.x;
  if (i < n) p[i] = v;
}

// ===========================================================================
extern "C" void kernel_launch(void* const* d_in, const int* in_sizes, int n_in,
                              void* d_out, int out_size, void* d_ws, size_t ws_size,
                              hipStream_t stream) {
  const int* code   = (const int*)d_in[0];
  const int* ncode  = (const int*)d_in[1];
  const float* emb  = (const float*)d_in[2];
  const float* pos  = (const float*)d_in[3];
  const float* Wq   = (const float*)d_in[4];
  const float* bq   = (const float*)d_in[5];
  const float* Wk   = (const float*)d_in[6];
  const float* bk   = (const float*)d_in[7];
  const float* Wv   = (const float*)d_in[8];
  const float* bv   = (const float*)d_in[9];
  const float* Wo   = (const float*)d_in[10];
  const float* bo   = (const float*)d_in[11];
  const float* ln1g = (const float*)d_in[12];
  const float* ln1b = (const float*)d_in[13];
  const float* ln2g = (const float*)d_in[14];
  const float* ln2b = (const float*)d_in[15];
  const float* Wc1  = (const float*)d_in[16];
  const float* bc1  = (const float*)d_in[17];
  const float* Wc2  = (const float*)d_in[18];
  const float* bc2  = (const float*)d_in[19];
  const float* cW1  = (const float*)d_in[20];
  const float* cb1  = (const float*)d_in[21];
  const float* clng = (const float*)d_in[22];
  const float* clnb = (const float*)d_in[23];
  const float* cW2  = (const float*)d_in[24];
  const float* cb2  = (const float*)d_in[25];
  float* out = (float*)d_out;
  (void)in_sizes; (void)n_in; (void)out_size;

  // sizes (f16 units)
  const long WSLOT = 5308416;    // 27*768*256 (max per-conv weight, QKV fused)
  const long HSL   = 2097152;    // per-slice H per comp
  const long QSL   = 6291456;    // per-slice QKV interleaved per comp
  const long T1SL  = 4194304;    // per-slice T1 per comp
  const long CLMIN = 21233664;   // classifier slab minimum

  auto needf = [&](int ns) -> size_t {
    long slab = (long)ns * 2 * QSL;
    if (slab < CLMIN) slab = CLMIN;
    return (size_t)(2 * WSLOT + 2 * 12582912L + slab) * 2 + 6912 * 4 + 768 * 4 + 4096;
  };
  int NS = 0;
  if      (ws_size >= needf(6)) NS = 6;
  else if (ws_size >= needf(3)) NS = 3;
  else if (ws_size >= needf(2)) NS = 2;
  else if (ws_size >= needf(1)) NS = 1;
  if (NS == 0) {
    fill_kernel<<<dim3(109), 256, 0, stream>>>(out + kSC, 27649, -1.0f);
    return;
  }
  long slab_f16 = (long)NS * 2 * QSL;
  if (slab_f16 < CLMIN) slab_f16 = CLMIN;

  f16* wh = (f16*)d_ws;
  f16* wl = wh + WSLOT;
  f16* Hh = wl + WSLOT;
  f16* Hl = Hh + 12582912;
  f16* S  = Hl + 12582912;
  float* partial = (float*)(S + slab_f16);
  float* bcat = partial + 6912;

  const size_t WQKVO = 27u * 256 * 256;
  const size_t WC1SZ = 27u * 256 * 512;
  const size_t WC2SZ = 27u * 512 * 256;

  embed_kernel<<<dim3(49152), 256, 0, stream>>>(code, ncode, emb, pos, Hh, Hl);

  const int nchunk = 6 / NS;
  f16* qkvh = S;
  f16* qkvl = S + (long)NS * QSL;
  f16* t1h  = S;
  f16* t1l  = S + (long)NS * T1SL;

  for (int l = 0; l < 2; ++l) {
    const float* wq = Wq + (size_t)l * WQKVO;
    const float* wk = Wk + (size_t)l * WQKVO;
    const float* wv = Wv + (size_t)l * WQKVO;
    const float* wo = Wo + (size_t)l * WQKVO;
    const float* wc1 = Wc1 + (size_t)l * WC1SZ;
    const float* wc2 = Wc2 + (size_t)l * WC2SZ;
    bpack_kernel<<<dim3(3), 256, 0, stream>>>(bq + l * 256, bk + l * 256, bv + l * 256, bcat);
    for (int ch = 0; ch < nchunk; ++ch) {
      f16* Xh = Hh + (long)ch * NS * HSL;
      f16* Xl = Hl + (long)ch * NS * HSL;
      // fused QKV conv
      wsplit_kernel<<<dim3(6912), 256, 0, stream>>>(wq, wh, wl, 27, 256, 256, 768, 0);
      wsplit_kernel<<<dim3(6912), 256, 0, stream>>>(wk, wh, wl, 27, 256, 256, 768, 256);
      wsplit_kernel<<<dim3(6912), 256, 0, stream>>>(wv, wh, wl, 27, 256, 256, 768, 512);
      conv14_kernel<256, 768, 0, 0><<<dim3(64 * 6 * NS), 256, 0, stream>>>(
          Xh, Xl, HSL, 256, wh, wl, bcat, qkvh, qkvl, QSL, 768, NS);
      attn_kernel<<<dim3(NS * 1024), 256, 0, stream>>>(qkvh, qkvl);
      // O projection with fused residual into H
      wsplit_kernel<<<dim3(6912), 256, 0, stream>>>(wo, wh, wl, 27, 256, 256, 256, 0);
      conv14_kernel<256, 256, 0, 1><<<dim3(64 * 2 * NS), 256, 0, stream>>>(
          qkvh, qkvl, QSL, 768, wh, wl, bo + l * 256, Xh, Xl, HSL, 256, NS);
      ln_kernel<<<dim3(2048 * NS), 256, 0, stream>>>(Xh, Xl, ln1g + l * 256, ln1b + l * 256);
      // FFN1 with fused gelu
      wsplit_kernel<<<dim3(13824), 256, 0, stream>>>(wc1, wh, wl, 27, 256, 512, 512, 0);
      conv14_kernel<256, 512, 1, 0><<<dim3(64 * 4 * NS), 256, 0, stream>>>(
          Xh, Xl, HSL, 256, wh, wl, bc1 + l * 512, t1h, t1l, T1SL, 512, NS);
      // FFN2 with fused residual
      wsplit_kernel<<<dim3(13824), 256, 0, stream>>>(wc2, wh, wl, 27, 512, 256, 256, 0);
      conv14_kernel<512, 256, 0, 1><<<dim3(64 * 2 * NS), 256, 0, stream>>>(
          t1h, t1l, T1SL, 512, wh, wl, bc2 + l * 256, Xh, Xl, HSL, 256, NS);
      ln_kernel<<<dim3(2048 * NS), 256, 0, stream>>>(Xh, Xl, ln2g + l * 256, ln2b + l * 256);
    }
  }

  // ---- classifier, chunked by n ----
  for (int n = 0; n < 2; ++n) {
    f16* Z1h = S;
    f16* Z1l = S + 3538944;
    f16* Xch = S + 7077888;
    f16* Xcl = S + 10616832;
    float* Z2 = (float*)(S + 7077888);   // overwrites Xc (dead after gemm1)
    gather_kernel<<<dim3(13824), 256, 0, stream>>>(Hh, Hl, n, Xch, Xcl);
    wsplit_kernel<<<dim3(256), 256, 0, stream>>>(cW1, wh, wl, 1, 256, 256, 256, 0);
    gemm_kernel<256, 256, false><<<dim3(216, 4), 256, 0, stream>>>(Xch, Xcl, wh, wl, cb1, Z1h, Z1l, nullptr);
    ln_gelu_kernel<<<dim3(3456), 256, 0, stream>>>(Z1h, Z1l, clng, clnb);
    wsplit_kernel<<<dim3(512), 256, 0, stream>>>(cW2, wh, wl, 1, 256, 512, 512, 0);
    gemm_kernel<256, 512, true><<<dim3(216, 8), 256, 0, stream>>>(Z1h, Z1l, wh, wl, cb2, nullptr, nullptr, Z2);
    transpose_kernel<<<dim3(432, 16), 256, 0, stream>>>(Z2, out + (long)n * 512 * 13824);
    loss_pred_kernel<<<dim3(3456), 256, 0, stream>>>(Z2, ncode + n * 13824,
                                                     out + kSC + 1 + n * 13824, partial + n * 3456);
  }
  loss_final_kernel<<<dim3(1), 256, 0, stream>>>(partial, out + kSC);
}

// Round 15
// 6748.120 us; speedup vs baseline: 8.2817x; 1.1036x over previous
//
#include <hip/hip_runtime.h>

// ---------------------------------------------------------------------------
// Transformer_90426241450054 — MI355X (round 15)
// Numerics: proven 3-mult split-f16 pairs (x ~= hi + lo*2^-11, fp32 parity).
// conv15 = R14's conv14 (proven best: 128x128 tile, 64 KB LDS, one
// barrier/tap, 2 blocks/CU, tap-skip, setprio) with the tap loop unrolled
// og(3) x oi(9, full) so dv/dw fold to compile-time, plus algebraic
// hoisting of the A-swizzle (depends only on ww) ->大 cut in per-tap VALU.
// ---------------------------------------------------------------------------

typedef _Float16 f16;
typedef __attribute__((ext_vector_type(8))) _Float16 f16x8;
typedef __attribute__((ext_vector_type(4))) _Float16 f16x4;
typedef __attribute__((ext_vector_type(4))) float f32x4;

static constexpr long kSC = 14155776;               // score elems = 2*512*13824
static constexpr float kDS = 4.8828125e-4f;         // 2^-11

#define MFMA16(a, b, c) __builtin_amdgcn_mfma_f32_16x16x32_f16((a), (b), (c), 0, 0, 0)

__device__ __forceinline__ void gl16(const void* g, void* l) {
  __builtin_amdgcn_global_load_lds((const __attribute__((address_space(1))) void*)g,
                                   (__attribute__((address_space(3))) void*)l,
                                   16, 0, 0);
}

__device__ __forceinline__ float wave_sum_f(float x) {
#pragma unroll
  for (int m = 32; m; m >>= 1) x += __shfl_xor(x, m);
  return x;
}

__device__ __forceinline__ void split2(float x, f16* h, f16* l) {
  f16 hh = (f16)x;
  *h = hh;
  *l = (f16)((x - (float)hh) * 2048.0f);
}

__device__ __forceinline__ float rec2(f16 h, f16 l) {
  return (float)h + (float)l * kDS;
}

__device__ __forceinline__ float gelu_exact(float x) {
  return 0.5f * x * (1.0f + erff(x * 0.70710678118654752f));
}

// ---------------- weight split: [G][Ci][Co] f32 -> [G][CoTot][Ci] pair ------
__global__ __launch_bounds__(256) void wsplit_kernel(
    const float* __restrict__ src, f16* __restrict__ hi, f16* __restrict__ lo,
    int G, int Ci, int Co, int CoTot, int co0) {
  long n = (long)G * Ci * Co;
  long i = (long)blockIdx.x * 256 + threadIdx.x;
  if (i >= n) return;
  int co = (int)(i % Co);
  long t = i / Co;
  int ci = (int)(t % Ci);
  int g  = (int)(t / Ci);
  float x = src[i];
  long o = ((long)g * CoTot + co0 + co) * Ci + ci;
  split2(x, hi + o, lo + o);
}

// ---------------- bias concat (q,k,v -> 768) -------------------------------
__global__ __launch_bounds__(256) void bpack_kernel(
    const float* __restrict__ bq, const float* __restrict__ bk,
    const float* __restrict__ bv, float* __restrict__ dst) {
  int i = blockIdx.x * 256 + threadIdx.x;
  if (i < 256) dst[i] = bq[i];
  else if (i < 512) dst[i] = bk[i - 256];
  else if (i < 768) dst[i] = bv[i - 512];
}

// ---------------- embedding + pos -> H pair --------------------------------
__global__ __launch_bounds__(256) void embed_kernel(
    const int* __restrict__ code, const int* __restrict__ ncode,
    const float* __restrict__ emb, const float* __restrict__ pos,
    f16* __restrict__ Hh, f16* __restrict__ Hl) {
  int tok = blockIdx.x;            // g*8192 + s*512 + vox
  int e = threadIdx.x;
  int g = tok >> 13;
  int rem = tok & 8191;
  int s = rem >> 9;
  int vox = rem & 511;
  int n = g / 3, c = g - 3 * n;
  int idx;
  if (s < 8) idx = code[((n * 8 + s) * 3 + c) * 512 + vox];
  else       idx = ncode[((n * 9 + (s - 8)) * 3 + c) * 512 + vox];
  float val = emb[idx * 256 + e] + pos[s * 256 + e];
  long o = (long)tok * 256 + e;
  split2(val, Hh + o, Hl + o);
}

// ---------------- conv3d 3x3x3 SAME, v15 -----------------------------------
// = conv14 schedule with og(3) x oi(9 fully unrolled) tap loop:
// dv,dw compile-time; A-swizzle hoisted (depends only on ww).
template <int CIN, int COUTT, int ACT, int RESID>
__global__ __launch_bounds__(256, 2) void conv15_kernel(
    const f16* __restrict__ Xh, const f16* __restrict__ Xl, long xz_s, int xr,
    const f16* __restrict__ Wh, const f16* __restrict__ Wl,
    const float* __restrict__ bias,
    f16* __restrict__ Yh, f16* __restrict__ Yl, long yz_s, int yr, int nz) {
  constexpr int KB = CIN / 32;
  constexpr int NY = COUTT / 128;
  __shared__ __align__(16) f16 lsAll[32768];   // 64 KB
  // f16 offsets: A0 [0,8192) A1 [8192,16384)
  //              B: 16384 + buf*8192 + comp*4096 + row*32 + slot*8

  const int nwg = 64 * NY * nz;
  const int q = nwg >> 3;
  const int bid = blockIdx.x;
  const int wg = (bid & 7) * q + (bid >> 3);
  const int y = wg / (64 * nz);
  const int rem = wg - y * (64 * nz);
  const int z = rem >> 6;
  const int mt = rem & 63;
  const int img = mt >> 2, up = mt & 3;
  const int u0 = up * 2;
  const int coutb0 = y * 128;

  const int tid = threadIdx.x;
  const int wid = tid >> 6, lane = tid & 63;
  const int wm = wid >> 1, wn = wid & 1;
  const int l15 = lane & 15, lk = lane >> 4;
  const int v0 = l15 >> 3, w0 = l15 & 7;     // A-frag voxel coords

  const long xz = (long)z * xz_s;
  const long yz = (long)z * yz_s;

  f32x4 aA[4][4], aB[4][4];
#pragma unroll
  for (int mf = 0; mf < 4; ++mf)
#pragma unroll
    for (int nf = 0; nf < 4; ++nf) {
      float bv = bias[coutb0 + wn * 64 + nf * 16 + l15];
      aA[mf][nf] = (f32x4){bv, bv, bv, bv};
      aB[mf][nf] = (f32x4){0.f, 0.f, 0.f, 0.f};
    }

  const int swrow = tid >> 2;           // staging row
  const int sswz = (tid & 3) ^ ((tid >> 3) & 3);  // staged col swizzle

  auto stageA = [&](int kb) {
#pragma unroll
    for (int j = 0; j < 4; ++j) {
      const int uu = u0 - 1 + j;
      if (uu < 0 || uu >= 8) continue;  // block-uniform
      const long g = xz + ((long)(img * 512 + uu * 64 + swrow)) * (long)xr
                     + kb * 32 + sswz * 8;
      gl16(Xh + g, &lsAll[j * 2048 + tid * 8]);
      gl16(Xl + g, &lsAll[8192 + j * 2048 + tid * 8]);
    }
  };
  auto stageB = [&](int o, int kb, int buf) {
    const int wb = 16384 + buf * 8192;
#pragma unroll
    for (int i = 0; i < 2; ++i) {
      const long g = ((long)o * COUTT + coutb0 + i * 64 + swrow) * (long)CIN
                     + kb * 32 + sswz * 8;
      gl16(Wh + g, &lsAll[wb + i * 2048 + tid * 8]);
      gl16(Wl + g, &lsAll[wb + 4096 + i * 2048 + tid * 8]);
    }
  };
  // dv,dw are compile-time constants at every call site (oi fully unrolled).
  auto compute = [&](int du, int dv, int dw, int buf) {
    const int gu = u0 + wm + du;
    if ((unsigned)gu >= 8u) return;     // wave-uniform tap skip
    const int p = wm + 1 + du;
    const int wb = 16384 + buf * 8192;
    f16x8 bh[4], bl[4];
#pragma unroll
    for (int nf = 0; nf < 4; ++nf) {
      const int rb = wn * 64 + nf * 16 + l15;
      const int sw = lk ^ ((rb >> 1) & 3);
      bh[nf] = *(const f16x8*)&lsAll[wb + rb * 32 + sw * 8];
      bl[nf] = *(const f16x8*)&lsAll[wb + 4096 + rb * 32 + sw * 8];
    }
    // A-swizzle depends only on ww (bits 1-2 of vv*8+ww are ww's bits 1-2)
    const int ww = w0 + dw;
    const bool wok = (unsigned)ww < 8u;
    const int sw8 = (lk ^ ((ww >> 1) & 3)) * 8;
    const int abase = p * 2048 + ww * 32 + sw8;     // + vv*256 per mf
    __builtin_amdgcn_s_setprio(1);
#pragma unroll
    for (int mf = 0; mf < 4; ++mf) {
      const int vv = mf * 2 + v0 + dv;
      const bool ok = wok && ((unsigned)vv < 8u);
      f16x8 ah = {0, 0, 0, 0, 0, 0, 0, 0};
      f16x8 al = {0, 0, 0, 0, 0, 0, 0, 0};
      if (ok) {
        const int ad = abase + vv * 256;
        ah = *(const f16x8*)&lsAll[ad];
        al = *(const f16x8*)&lsAll[8192 + ad];
      }
#pragma unroll
      for (int nf = 0; nf < 4; ++nf) {
        aA[mf][nf] = MFMA16(ah, bh[nf], aA[mf][nf]);
        aB[mf][nf] = MFMA16(ah, bl[nf], aB[mf][nf]);
        aB[mf][nf] = MFMA16(al, bh[nf], aB[mf][nf]);
      }
    }
    __builtin_amdgcn_s_setprio(0);
  };

  // prologue
  stageA(0);
  stageB(0, 0, 0);
  __syncthreads();

  int cur = 0;
#pragma unroll 1
  for (int kb = 0; kb < KB; ++kb) {
#pragma unroll 1
    for (int og = 0; og < 3; ++og) {
      const int du = og - 1;
#pragma unroll
      for (int oi = 0; oi < 9; ++oi) {
        const int o = og * 9 + oi;                  // og runtime, oi literal
        if (o < 26)           stageB(o + 1, kb, cur ^ 1);
        else if (kb + 1 < KB) stageB(0, kb + 1, cur ^ 1);
        compute(du, oi / 3 - 1, oi % 3 - 1, cur);   // dv,dw compile-time
        __syncthreads();
        cur ^= 1;
      }
    }
    if (kb + 1 < KB) {
      stageA(kb + 1);
      __syncthreads();
    }
  }

  // epilogue: two row-half passes through LDS (padded stride, conflict-free)
  float* sY = (float*)lsAll;            // [64][132]
#pragma unroll 1
  for (int rh = 0; rh < 2; ++rh) {
    if (wm == rh) {
#pragma unroll
      for (int mf = 0; mf < 4; ++mf)
#pragma unroll
        for (int nf = 0; nf < 4; ++nf)
#pragma unroll
          for (int j = 0; j < 4; ++j) {
            const int row = mf * 16 + lk * 4 + j;
            const int col = wn * 64 + nf * 16 + l15;
            sY[row * 132 + col] = aA[mf][nf][j] + aB[mf][nf][j] * kDS;
          }
    }
    __syncthreads();
#pragma unroll
    for (int it = 0; it < 2; ++it) {
      const int row = it * 32 + (tid >> 3);
      const int c0 = (tid & 7) * 16;
      const long grow = (long)img * 512 + (u0 + rh) * 64 + row;
      const long gidx = yz + grow * (long)yr + coutb0 + c0;
      float yv[16];
#pragma unroll
      for (int i2 = 0; i2 < 16; ++i2) yv[i2] = sY[row * 132 + c0 + i2];
      if (ACT) {
#pragma unroll
        for (int i2 = 0; i2 < 16; ++i2) yv[i2] = gelu_exact(yv[i2]);
      }
      if (RESID) {
        f16x8 r0h = *(const f16x8*)&Yh[gidx];
        f16x8 r1h = *(const f16x8*)&Yh[gidx + 8];
        f16x8 r0l = *(const f16x8*)&Yl[gidx];
        f16x8 r1l = *(const f16x8*)&Yl[gidx + 8];
#pragma unroll
        for (int i2 = 0; i2 < 8; ++i2) {
          yv[i2] += rec2(r0h[i2], r0l[i2]);
          yv[8 + i2] += rec2(r1h[i2], r1l[i2]);
        }
      }
      f16x8 h0, h1, l0, l1;
#pragma unroll
      for (int i2 = 0; i2 < 8; ++i2) {
        f16 a, b;
        split2(yv[i2], &a, &b); h0[i2] = a; l0[i2] = b;
        split2(yv[8 + i2], &a, &b); h1[i2] = a; l1[i2] = b;
      }
      *(f16x8*)&Yh[gidx] = h0;
      *(f16x8*)&Yh[gidx + 8] = h1;
      *(f16x8*)&Yl[gidx] = l0;
      *(f16x8*)&Yl[gidx + 8] = l1;
    }
    __syncthreads();
  }
}

// ---------------- plain GEMM (classifier), pair in, pair or f32 out --------
template <int K_, int COUT, bool F32OUT>
__global__ __launch_bounds__(256) void gemm_kernel(
    const f16* __restrict__ Xh, const f16* __restrict__ Xl,
    const f16* __restrict__ Wh, const f16* __restrict__ Wl,
    const float* __restrict__ bias,
    f16* __restrict__ Yh, f16* __restrict__ Yl, float* __restrict__ Yf) {
  const int m0 = blockIdx.x * 64;
  const int coutb = blockIdx.y * 64;
  const int tid = threadIdx.x;
  const int wid = tid >> 6, lane = tid & 63;
  const int l15 = lane & 15, lk = lane >> 4;
  const int arow = m0 + wid * 16 + l15;

  f32x4 accA[4], accB[4];
#pragma unroll
  for (int cg = 0; cg < 4; ++cg) {
    float bv = bias[coutb + cg * 16 + l15];
    accA[cg] = (f32x4){bv, bv, bv, bv};
    accB[cg] = (f32x4){0.f, 0.f, 0.f, 0.f};
  }
  const f16* pah = Xh + (long)arow * K_ + lk * 8;
  const f16* pal = Xl + (long)arow * K_ + lk * 8;
  const f16* pbh = Wh + ((long)coutb + l15) * K_ + lk * 8;
  const f16* pbl = Wl + ((long)coutb + l15) * K_ + lk * 8;
#pragma unroll 2
  for (int kb = 0; kb < K_ / 32; ++kb) {
    f16x8 ah = *(const f16x8*)(pah + kb * 32);
    f16x8 al = *(const f16x8*)(pal + kb * 32);
#pragma unroll
    for (int cg = 0; cg < 4; ++cg) {
      f16x8 bh = *(const f16x8*)(pbh + (long)cg * 16 * K_ + kb * 32);
      f16x8 bl = *(const f16x8*)(pbl + (long)cg * 16 * K_ + kb * 32);
      accA[cg] = MFMA16(ah, bh, accA[cg]);
      accB[cg] = MFMA16(ah, bl, accB[cg]);
      accB[cg] = MFMA16(al, bh, accB[cg]);
    }
  }
  const long ybase = ((long)m0 + wid * 16) * (long)COUT + coutb;
#pragma unroll
  for (int cg = 0; cg < 4; ++cg)
#pragma unroll
    for (int j = 0; j < 4; ++j) {
      int r = lk * 4 + j;
      float y = accA[cg][j] + accB[cg][j] * kDS;
      long idx = ybase + (long)r * COUT + cg * 16 + l15;
      if (F32OUT) Yf[idx] = y;
      else        split2(y, Yh + idx, Yl + idx);
    }
}

// ---------------- attention on interleaved QKV [tok][768] pairs ------------
__global__ __launch_bounds__(256) void attn_kernel(
    f16* __restrict__ QKVh, f16* __restrict__ QKVl) {
  __shared__ float sq[4][16][33];
  __shared__ float sk[4][16][33];
  __shared__ float sv[4][16][33];
  __shared__ float ss[4][16][17];
  const int wid = threadIdx.x >> 6, lane = threadIdx.x & 63;
  const int p = blockIdx.x * 4 + wid;
  const int cs = p >> 12;
  const int loc = p & 4095;
  const int nh = loc >> 9;
  const int vox = loc & 511;
  const int srow = lane >> 2;
  const int dp = (lane & 3) * 8;
  const long sbase = (long)cs * 6291456;
  const long base = sbase + ((long)(srow * 512 + vox)) * 768 + nh * 32 + dp;

  {
    f16x8 qh = *(const f16x8*)(QKVh + base);
    f16x8 ql = *(const f16x8*)(QKVl + base);
    f16x8 kh = *(const f16x8*)(QKVh + base + 256);
    f16x8 kl = *(const f16x8*)(QKVl + base + 256);
    f16x8 vh = *(const f16x8*)(QKVh + base + 512);
    f16x8 vl = *(const f16x8*)(QKVl + base + 512);
#pragma unroll
    for (int j = 0; j < 8; ++j) {
      sq[wid][srow][dp + j] = rec2(qh[j], ql[j]);
      sk[wid][srow][dp + j] = rec2(kh[j], kl[j]);
      sv[wid][srow][dp + j] = rec2(vh[j], vl[j]);
    }
  }
  __syncthreads();
#pragma unroll
  for (int pp = 0; pp < 4; ++pp) {
    int pr = lane * 4 + pp;
    int qi = pr >> 4, kt = pr & 15;
    float s = 0.f;
#pragma unroll
    for (int d = 0; d < 32; ++d) s += sq[wid][qi][d] * sk[wid][kt][d];
    bool allowed = (kt < 8) || (kt <= qi);
    ss[wid][qi][kt] = allowed ? s * 0.17677669529663687f : -1e30f;
  }
  __syncthreads();
  if (lane < 16) {
    float m = -1e30f;
#pragma unroll
    for (int t = 0; t < 16; ++t) m = fmaxf(m, ss[wid][lane][t]);
    float ex[16];
    float sum = 0.f;
#pragma unroll
    for (int t = 0; t < 16; ++t) { ex[t] = expf(ss[wid][lane][t] - m); sum += ex[t]; }
    float inv = 1.0f / sum;
#pragma unroll
    for (int t = 0; t < 16; ++t) ss[wid][lane][t] = ex[t] * inv;
  }
  __syncthreads();
  float o[8] = {0, 0, 0, 0, 0, 0, 0, 0};
#pragma unroll
  for (int t = 0; t < 16; ++t) {
    float a = ss[wid][srow][t];
#pragma unroll
    for (int j = 0; j < 8; ++j) o[j] += a * sv[wid][t][dp + j];
  }
#pragma unroll
  for (int j = 0; j < 8; ++j) split2(o[j], QKVh + base + j, QKVl + base + j);
}

// ---------------- LayerNorm in place on H pair -----------------------------
__global__ __launch_bounds__(256) void ln_kernel(
    f16* __restrict__ Hh, f16* __restrict__ Hl,
    const float* __restrict__ gam, const float* __restrict__ bet) {
  const int wid = threadIdx.x >> 6, lane = threadIdx.x & 63;
  const long tok = (long)blockIdx.x * 4 + wid;
  const long base = tok * 256 + lane * 4;
  f16x4 hh = *(const f16x4*)(Hh + base);
  f16x4 hl = *(const f16x4*)(Hl + base);
  float v0 = rec2(hh[0], hl[0]), v1 = rec2(hh[1], hl[1]);
  float v2 = rec2(hh[2], hl[2]), v3 = rec2(hh[3], hl[3]);
  float mu = wave_sum_f(v0 + v1 + v2 + v3) * (1.0f / 256.0f);
  float d0 = v0 - mu, d1 = v1 - mu, d2 = v2 - mu, d3 = v3 - mu;
  float var = wave_sum_f(d0 * d0 + d1 * d1 + d2 * d2 + d3 * d3) * (1.0f / 256.0f);
  float rs = rsqrtf(var + 1e-5f);
  float4 gv = *(const float4*)(gam + lane * 4);
  float4 bv = *(const float4*)(bet + lane * 4);
  float y0 = d0 * rs * gv.x + bv.x, y1 = d1 * rs * gv.y + bv.y;
  float y2 = d2 * rs * gv.z + bv.z, y3 = d3 * rs * gv.w + bv.w;
  f16x4 oh, ol;
  f16 a, b2;
  split2(y0, &a, &b2); oh[0] = a; ol[0] = b2;
  split2(y1, &a, &b2); oh[1] = a; ol[1] = b2;
  split2(y2, &a, &b2); oh[2] = a; ol[2] = b2;
  split2(y3, &a, &b2); oh[3] = a; ol[3] = b2;
  *(f16x4*)(Hh + base) = oh;
  *(f16x4*)(Hl + base) = ol;
}

// ---------------- classifier LN + GELU in-place (pairs) --------------------
__global__ __launch_bounds__(256) void ln_gelu_kernel(
    f16* __restrict__ Zh, f16* __restrict__ Zl,
    const float* __restrict__ gam, const float* __restrict__ bet) {
  const int wid = threadIdx.x >> 6, lane = threadIdx.x & 63;
  const long tok = (long)blockIdx.x * 4 + wid;
  const long base = tok * 256 + lane * 4;
  f16x4 hh = *(const f16x4*)(Zh + base);
  f16x4 hl = *(const f16x4*)(Zl + base);
  float v0 = rec2(hh[0], hl[0]), v1 = rec2(hh[1], hl[1]);
  float v2 = rec2(hh[2], hl[2]), v3 = rec2(hh[3], hl[3]);
  float mu = wave_sum_f(v0 + v1 + v2 + v3) * (1.0f / 256.0f);
  float d0 = v0 - mu, d1 = v1 - mu, d2 = v2 - mu, d3 = v3 - mu;
  float var = wave_sum_f(d0 * d0 + d1 * d1 + d2 * d2 + d3 * d3) * (1.0f / 256.0f);
  float rs = rsqrtf(var + 1e-5f);
  float4 gv = *(const float4*)(gam + lane * 4);
  float4 bv = *(const float4*)(bet + lane * 4);
  float y0 = gelu_exact(d0 * rs * gv.x + bv.x);
  float y1 = gelu_exact(d1 * rs * gv.y + bv.y);
  float y2 = gelu_exact(d2 * rs * gv.z + bv.z);
  float y3 = gelu_exact(d3 * rs * gv.w + bv.w);
  f16x4 oh, ol;
  f16 a, b2;
  split2(y0, &a, &b2); oh[0] = a; ol[0] = b2;
  split2(y1, &a, &b2); oh[1] = a; ol[1] = b2;
  split2(y2, &a, &b2); oh[2] = a; ol[2] = b2;
  split2(y3, &a, &b2); oh[3] = a; ol[3] = b2;
  *(f16x4*)(Zh + base) = oh;
  *(f16x4*)(Zl + base) = ol;
}

// ---------------- classifier token gather (pair copy) ----------------------
__global__ __launch_bounds__(256) void gather_kernel(
    const f16* __restrict__ Hh, const f16* __restrict__ Hl, int n,
    f16* __restrict__ Xh, f16* __restrict__ Xl) {
  const int tc = blockIdx.x;       // (s2*3+c)*512+vox
  const int e = threadIdx.x;
  const int s2 = tc / 1536;
  int r = tc - s2 * 1536;
  const int c = r >> 9;
  const int vox = r & 511;
  const int g = n * 3 + c;
  const int s = 7 + s2;
  const long src = ((long)(g * 16 + s) * 512 + vox) * 256 + e;
  const long dst = (long)tc * 256 + e;
  Xh[dst] = Hh[src];
  Xl[dst] = Hl[src];
}

// ---------------- score transpose: Z2[t][k] -> out[k][t] (per n) -----------
__global__ __launch_bounds__(256) void transpose_kernel(
    const float* __restrict__ Z2, float* __restrict__ out) {
  __shared__ float tile[32][33];
  const int t0 = blockIdx.x * 32;
  const int k0 = blockIdx.y * 32;
  const int tx = threadIdx.x & 31;
  const int ty = threadIdx.x >> 5;
#pragma unroll
  for (int i = 0; i < 32; i += 8)
    tile[ty + i][tx] = Z2[((long)(t0 + ty + i)) * 512 + k0 + tx];
  __syncthreads();
#pragma unroll
  for (int i = 0; i < 32; i += 8)
    out[((long)(k0 + ty + i)) * 13824 + t0 + tx] = tile[tx][ty + i];
}

// ---------------- loss + pred (per n chunk) --------------------------------
__global__ __launch_bounds__(256) void loss_pred_kernel(
    const float* __restrict__ Z2, const int* __restrict__ ncode,
    float* __restrict__ pred, float* __restrict__ partial) {
  __shared__ float sh[4];
  const int wid = threadIdx.x >> 6, lane = threadIdx.x & 63;
  const int tok = blockIdx.x * 4 + wid;
  const float* row = Z2 + (long)tok * 512;
  float4 a = *(const float4*)(row + lane * 8);
  float4 b = *(const float4*)(row + lane * 8 + 4);
  float vals[8] = {a.x, a.y, a.z, a.w, b.x, b.y, b.z, b.w};
  float mx = vals[0];
  int mi = lane * 8;
#pragma unroll
  for (int j = 1; j < 8; ++j)
    if (vals[j] > mx) { mx = vals[j]; mi = lane * 8 + j; }
#pragma unroll
  for (int m = 1; m < 64; m <<= 1) {
    float ox = __shfl_xor(mx, m);
    int oi = __shfl_xor(mi, m);
    if (ox > mx || (ox == mx && oi < mi)) { mx = ox; mi = oi; }
  }
  float se = 0.f;
#pragma unroll
  for (int j = 0; j < 8; ++j) se += expf(vals[j] - mx);
  se = wave_sum_f(se);
  if (lane == 0) {
    int tgt = ncode[tok];
    float nll = mx + logf(se) - row[tgt];
    pred[tok] = (float)mi;
    sh[wid] = nll;
  }
  __syncthreads();
  if (threadIdx.x == 0) partial[blockIdx.x] = sh[0] + sh[1] + sh[2] + sh[3];
}

__global__ __launch_bounds__(256) void loss_final_kernel(
    const float* __restrict__ partial, float* __restrict__ out) {
  __shared__ float sh[4];
  float s = 0.f;
  for (int i = threadIdx.x; i < 6912; i += 256) s += partial[i];
  s = wave_sum_f(s);
  if ((threadIdx.x & 63) == 0) sh[threadIdx.x >> 6] = s;
  __syncthreads();
  if (threadIdx.x == 0) out[0] = (sh[0] + sh[1] + sh[2] + sh[3]) * (1.0f / 27648.0f);
}

// ---------------- sentinel fill --------------------------------------------
__global__ __launch_bounds__(256) void fill_kernel(float* __restrict__ p, long n, float v) {
  long i = (long)blockIdx.x * 256 + threadIdx.x;
  if (i < n) p[i] = v;
}

// ===========================================================================
extern "C" void kernel_launch(void* const* d_in, const int* in_sizes, int n_in,
                              void* d_out, int out_size, void* d_ws, size_t ws_size,
                              hipStream_t stream) {
  const int* code   = (const int*)d_in[0];
  const int* ncode  = (const int*)d_in[1];
  const float* emb  = (const float*)d_in[2];
  const float* pos  = (const float*)d_in[3];
  const float* Wq   = (const float*)d_in[4];
  const float* bq   = (const float*)d_in[5];
  const float* Wk   = (const float*)d_in[6];
  const float* bk   = (const float*)d_in[7];
  const float* Wv   = (const float*)d_in[8];
  const float* bv   = (const float*)d_in[9];
  const float* Wo   = (const float*)d_in[10];
  const float* bo   = (const float*)d_in[11];
  const float* ln1g = (const float*)d_in[12];
  const float* ln1b = (const float*)d_in[13];
  const float* ln2g = (const float*)d_in[14];
  const float* ln2b = (const float*)d_in[15];
  const float* Wc1  = (const float*)d_in[16];
  const float* bc1  = (const float*)d_in[17];
  const float* Wc2  = (const float*)d_in[18];
  const float* bc2  = (const float*)d_in[19];
  const float* cW1  = (const float*)d_in[20];
  const float* cb1  = (const float*)d_in[21];
  const float* clng = (const float*)d_in[22];
  const float* clnb = (const float*)d_in[23];
  const float* cW2  = (const float*)d_in[24];
  const float* cb2  = (const float*)d_in[25];
  float* out = (float*)d_out;
  (void)in_sizes; (void)n_in; (void)out_size;

  // sizes (f16 units)
  const long WSLOT = 5308416;    // 27*768*256 (max per-conv weight, QKV fused)
  const long HSL   = 2097152;    // per-slice H per comp
  const long QSL   = 6291456;    // per-slice QKV interleaved per comp
  const long T1SL  = 4194304;    // per-slice T1 per comp
  const long CLMIN = 21233664;   // classifier slab minimum

  auto needf = [&](int ns) -> size_t {
    long slab = (long)ns * 2 * QSL;
    if (slab < CLMIN) slab = CLMIN;
    return (size_t)(2 * WSLOT + 2 * 12582912L + slab) * 2 + 6912 * 4 + 768 * 4 + 4096;
  };
  int NS = 0;
  if      (ws_size >= needf(6)) NS = 6;
  else if (ws_size >= needf(3)) NS = 3;
  else if (ws_size >= needf(2)) NS = 2;
  else if (ws_size >= needf(1)) NS = 1;
  if (NS == 0) {
    fill_kernel<<<dim3(109), 256, 0, stream>>>(out + kSC, 27649, -1.0f);
    return;
  }
  long slab_f16 = (long)NS * 2 * QSL;
  if (slab_f16 < CLMIN) slab_f16 = CLMIN;

  f16* wh = (f16*)d_ws;
  f16* wl = wh + WSLOT;
  f16* Hh = wl + WSLOT;
  f16* Hl = Hh + 12582912;
  f16* S  = Hl + 12582912;
  float* partial = (float*)(S + slab_f16);
  float* bcat = partial + 6912;

  const size_t WQKVO = 27u * 256 * 256;
  const size_t WC1SZ = 27u * 256 * 512;
  const size_t WC2SZ = 27u * 512 * 256;

  embed_kernel<<<dim3(49152), 256, 0, stream>>>(code, ncode, emb, pos, Hh, Hl);

  const int nchunk = 6 / NS;
  f16* qkvh = S;
  f16* qkvl = S + (long)NS * QSL;
  f16* t1h  = S;
  f16* t1l  = S + (long)NS * T1SL;

  for (int l = 0; l < 2; ++l) {
    const float* wq = Wq + (size_t)l * WQKVO;
    const float* wk = Wk + (size_t)l * WQKVO;
    const float* wv = Wv + (size_t)l * WQKVO;
    const float* wo = Wo + (size_t)l * WQKVO;
    const float* wc1 = Wc1 + (size_t)l * WC1SZ;
    const float* wc2 = Wc2 + (size_t)l * WC2SZ;
    bpack_kernel<<<dim3(3), 256, 0, stream>>>(bq + l * 256, bk + l * 256, bv + l * 256, bcat);
    for (int ch = 0; ch < nchunk; ++ch) {
      f16* Xh = Hh + (long)ch * NS * HSL;
      f16* Xl = Hl + (long)ch * NS * HSL;
      // fused QKV conv
      wsplit_kernel<<<dim3(6912), 256, 0, stream>>>(wq, wh, wl, 27, 256, 256, 768, 0);
      wsplit_kernel<<<dim3(6912), 256, 0, stream>>>(wk, wh, wl, 27, 256, 256, 768, 256);
      wsplit_kernel<<<dim3(6912), 256, 0, stream>>>(wv, wh, wl, 27, 256, 256, 768, 512);
      conv15_kernel<256, 768, 0, 0><<<dim3(64 * 6 * NS), 256, 0, stream>>>(
          Xh, Xl, HSL, 256, wh, wl, bcat, qkvh, qkvl, QSL, 768, NS);
      attn_kernel<<<dim3(NS * 1024), 256, 0, stream>>>(qkvh, qkvl);
      // O projection with fused residual into H
      wsplit_kernel<<<dim3(6912), 256, 0, stream>>>(wo, wh, wl, 27, 256, 256, 256, 0);
      conv15_kernel<256, 256, 0, 1><<<dim3(64 * 2 * NS), 256, 0, stream>>>(
          qkvh, qkvl, QSL, 768, wh, wl, bo + l * 256, Xh, Xl, HSL, 256, NS);
      ln_kernel<<<dim3(2048 * NS), 256, 0, stream>>>(Xh, Xl, ln1g + l * 256, ln1b + l * 256);
      // FFN1 with fused gelu
      wsplit_kernel<<<dim3(13824), 256, 0, stream>>>(wc1, wh, wl, 27, 256, 512, 512, 0);
      conv15_kernel<256, 512, 1, 0><<<dim3(64 * 4 * NS), 256, 0, stream>>>(
          Xh, Xl, HSL, 256, wh, wl, bc1 + l * 512, t1h, t1l, T1SL, 512, NS);
      // FFN2 with fused residual
      wsplit_kernel<<<dim3(13824), 256, 0, stream>>>(wc2, wh, wl, 27, 512, 256, 256, 0);
      conv15_kernel<512, 256, 0, 1><<<dim3(64 * 2 * NS), 256, 0, stream>>>(
          t1h, t1l, T1SL, 512, wh, wl, bc2 + l * 256, Xh, Xl, HSL, 256, NS);
      ln_kernel<<<dim3(2048 * NS), 256, 0, stream>>>(Xh, Xl, ln2g + l * 256, ln2b + l * 256);
    }
  }

  // ---- classifier, chunked by n ----
  for (int n = 0; n < 2; ++n) {
    f16* Z1h = S;
    f16* Z1l = S + 3538944;
    f16* Xch = S + 7077888;
    f16* Xcl = S + 10616832;
    float* Z2 = (float*)(S + 7077888);   // overwrites Xc (dead after gemm1)
    gather_kernel<<<dim3(13824), 256, 0, stream>>>(Hh, Hl, n, Xch, Xcl);
    wsplit_kernel<<<dim3(256), 256, 0, stream>>>(cW1, wh, wl, 1, 256, 256, 256, 0);
    gemm_kernel<256, 256, false><<<dim3(216, 4), 256, 0, stream>>>(Xch, Xcl, wh, wl, cb1, Z1h, Z1l, nullptr);
    ln_gelu_kernel<<<dim3(3456), 256, 0, stream>>>(Z1h, Z1l, clng, clnb);
    wsplit_kernel<<<dim3(512), 256, 0, stream>>>(cW2, wh, wl, 1, 256, 512, 512, 0);
    gemm_kernel<256, 512, true><<<dim3(216, 8), 256, 0, stream>>>(Z1h, Z1l, wh, wl, cb2, nullptr, nullptr, Z2);
    transpose_kernel<<<dim3(432, 16), 256, 0, stream>>>(Z2, out + (long)n * 512 * 13824);
    loss_pred_kernel<<<dim3(3456), 256, 0, stream>>>(Z2, ncode + n * 13824,
                                                     out + kSC + 1 + n * 13824, partial + n * 3456);
  }
  loss_final_kernel<<<dim3(1), 256, 0, stream>>>(partial, out + kSC);
}

// Round 16
// 6692.866 us; speedup vs baseline: 8.3500x; 1.0083x over previous
//
#include <hip/hip_runtime.h>

// ---------------------------------------------------------------------------
// Transformer_90426241450054 — MI355X (round 16)
// Numerics: proven 3-mult split-f16 pairs (x ~= hi + lo*2^-11, fp32 parity).
// conv16 = R15's conv15 (best: unrolled taps, hoisted A-swizzle) +
//   (1) zero-slot address-select for out-of-range A frags (1 cndmask vs ~16),
//   (2) precomputed B-fragment LDS offsets (boffs[4], thread-invariant),
//   (3) hoisted stageB global row bases.
// Schedule/barriers/buffering identical to R15.
// ---------------------------------------------------------------------------

typedef _Float16 f16;
typedef __attribute__((ext_vector_type(8))) _Float16 f16x8;
typedef __attribute__((ext_vector_type(4))) _Float16 f16x4;
typedef __attribute__((ext_vector_type(4))) float f32x4;

static constexpr long kSC = 14155776;               // score elems = 2*512*13824
static constexpr float kDS = 4.8828125e-4f;         // 2^-11

#define MFMA16(a, b, c) __builtin_amdgcn_mfma_f32_16x16x32_f16((a), (b), (c), 0, 0, 0)

__device__ __forceinline__ void gl16(const void* g, void* l) {
  __builtin_amdgcn_global_load_lds((const __attribute__((address_space(1))) void*)g,
                                   (__attribute__((address_space(3))) void*)l,
                                   16, 0, 0);
}

__device__ __forceinline__ float wave_sum_f(float x) {
#pragma unroll
  for (int m = 32; m; m >>= 1) x += __shfl_xor(x, m);
  return x;
}

__device__ __forceinline__ void split2(float x, f16* h, f16* l) {
  f16 hh = (f16)x;
  *h = hh;
  *l = (f16)((x - (float)hh) * 2048.0f);
}

__device__ __forceinline__ float rec2(f16 h, f16 l) {
  return (float)h + (float)l * kDS;
}

__device__ __forceinline__ float gelu_exact(float x) {
  return 0.5f * x * (1.0f + erff(x * 0.70710678118654752f));
}

// ---------------- weight split: [G][Ci][Co] f32 -> [G][CoTot][Ci] pair ------
__global__ __launch_bounds__(256) void wsplit_kernel(
    const float* __restrict__ src, f16* __restrict__ hi, f16* __restrict__ lo,
    int G, int Ci, int Co, int CoTot, int co0) {
  long n = (long)G * Ci * Co;
  long i = (long)blockIdx.x * 256 + threadIdx.x;
  if (i >= n) return;
  int co = (int)(i % Co);
  long t = i / Co;
  int ci = (int)(t % Ci);
  int g  = (int)(t / Ci);
  float x = src[i];
  long o = ((long)g * CoTot + co0 + co) * Ci + ci;
  split2(x, hi + o, lo + o);
}

// ---------------- bias concat (q,k,v -> 768) -------------------------------
__global__ __launch_bounds__(256) void bpack_kernel(
    const float* __restrict__ bq, const float* __restrict__ bk,
    const float* __restrict__ bv, float* __restrict__ dst) {
  int i = blockIdx.x * 256 + threadIdx.x;
  if (i < 256) dst[i] = bq[i];
  else if (i < 512) dst[i] = bk[i - 256];
  else if (i < 768) dst[i] = bv[i - 512];
}

// ---------------- embedding + pos -> H pair --------------------------------
__global__ __launch_bounds__(256) void embed_kernel(
    const int* __restrict__ code, const int* __restrict__ ncode,
    const float* __restrict__ emb, const float* __restrict__ pos,
    f16* __restrict__ Hh, f16* __restrict__ Hl) {
  int tok = blockIdx.x;            // g*8192 + s*512 + vox
  int e = threadIdx.x;
  int g = tok >> 13;
  int rem = tok & 8191;
  int s = rem >> 9;
  int vox = rem & 511;
  int n = g / 3, c = g - 3 * n;
  int idx;
  if (s < 8) idx = code[((n * 8 + s) * 3 + c) * 512 + vox];
  else       idx = ncode[((n * 9 + (s - 8)) * 3 + c) * 512 + vox];
  float val = emb[idx * 256 + e] + pos[s * 256 + e];
  long o = (long)tok * 256 + e;
  split2(val, Hh + o, Hl + o);
}

// ---------------- conv3d 3x3x3 SAME, v16 -----------------------------------
template <int CIN, int COUTT, int ACT, int RESID>
__global__ __launch_bounds__(256, 2) void conv16_kernel(
    const f16* __restrict__ Xh, const f16* __restrict__ Xl, long xz_s, int xr,
    const f16* __restrict__ Wh, const f16* __restrict__ Wl,
    const float* __restrict__ bias,
    f16* __restrict__ Yh, f16* __restrict__ Yl, long yz_s, int yr, int nz) {
  constexpr int KB = CIN / 32;
  constexpr int NY = COUTT / 128;
  constexpr int ZSLOT = 32768;                 // 8-f16 zero slot
  __shared__ __align__(16) f16 lsAll[32776];   // 64 KB + 16 B zero slot
  // f16 offsets: A0 [0,8192) A1 [8192,16384)
  //              B: 16384 + buf*8192 + comp*4096 + row*32 + slot*8
  //              zero slot: [32768,32776)

  const int nwg = 64 * NY * nz;
  const int q = nwg >> 3;
  const int bid = blockIdx.x;
  const int wg = (bid & 7) * q + (bid >> 3);
  const int y = wg / (64 * nz);
  const int rem = wg - y * (64 * nz);
  const int z = rem >> 6;
  const int mt = rem & 63;
  const int img = mt >> 2, up = mt & 3;
  const int u0 = up * 2;
  const int coutb0 = y * 128;

  const int tid = threadIdx.x;
  const int wid = tid >> 6, lane = tid & 63;
  const int wm = wid >> 1, wn = wid & 1;
  const int l15 = lane & 15, lk = lane >> 4;
  const int v0 = l15 >> 3, w0 = l15 & 7;     // A-frag voxel coords

  const long xz = (long)z * xz_s;
  const long yz = (long)z * yz_s;

  f32x4 aA[4][4], aB[4][4];
#pragma unroll
  for (int mf = 0; mf < 4; ++mf)
#pragma unroll
    for (int nf = 0; nf < 4; ++nf) {
      float bv = bias[coutb0 + wn * 64 + nf * 16 + l15];
      aA[mf][nf] = (f32x4){bv, bv, bv, bv};
      aB[mf][nf] = (f32x4){0.f, 0.f, 0.f, 0.f};
    }

  const int swrow = tid >> 2;           // staging row
  const int sswz = (tid & 3) ^ ((tid >> 3) & 3);  // staged col swizzle

  // thread-invariant B-fragment LDS offsets (constant-indexed -> registers)
  int boffs[4];
#pragma unroll
  for (int nf = 0; nf < 4; ++nf) {
    const int rb = wn * 64 + nf * 16 + l15;
    boffs[nf] = rb * 32 + (lk ^ ((rb >> 1) & 3)) * 8;
  }
  // hoisted stageB per-thread row bases (f16 elems, missing o*COUTT*CIN + kb*32)
  const long wrow0 = ((long)coutb0 + swrow) * (long)CIN + sswz * 8;
  const long wrow1 = ((long)coutb0 + 64 + swrow) * (long)CIN + sswz * 8;

  auto stageA = [&](int kb) {
#pragma unroll
    for (int j = 0; j < 4; ++j) {
      const int uu = u0 - 1 + j;
      if (uu < 0 || uu >= 8) continue;  // block-uniform
      const long g = xz + ((long)(img * 512 + uu * 64 + swrow)) * (long)xr
                     + kb * 32 + sswz * 8;
      gl16(Xh + g, &lsAll[j * 2048 + tid * 8]);
      gl16(Xl + g, &lsAll[8192 + j * 2048 + tid * 8]);
    }
  };
  auto stageB = [&](int o, int kb, int buf) {
    const int wb = 16384 + buf * 8192;
    const long ob = (long)o * COUTT * CIN + kb * 32;
    gl16(Wh + ob + wrow0, &lsAll[wb + tid * 8]);
    gl16(Wl + ob + wrow0, &lsAll[wb + 4096 + tid * 8]);
    gl16(Wh + ob + wrow1, &lsAll[wb + 2048 + tid * 8]);
    gl16(Wl + ob + wrow1, &lsAll[wb + 4096 + 2048 + tid * 8]);
  };
  // dv,dw are compile-time constants at every call site (oi fully unrolled).
  auto compute = [&](int du, int dv, int dw, int buf) {
    const int gu = u0 + wm + du;
    if ((unsigned)gu >= 8u) return;     // wave-uniform tap skip
    const int p = wm + 1 + du;
    const int wb = 16384 + buf * 8192;
    f16x8 bh[4], bl[4];
#pragma unroll
    for (int nf = 0; nf < 4; ++nf) {
      bh[nf] = *(const f16x8*)&lsAll[wb + boffs[nf]];
      bl[nf] = *(const f16x8*)&lsAll[wb + 4096 + boffs[nf]];
    }
    // A-swizzle depends only on ww (bits 1-2 of vv*8+ww are ww's bits 1-2)
    const int ww = w0 + dw;
    const bool wok = (unsigned)ww < 8u;
    const int sw8 = (lk ^ ((ww >> 1) & 3)) * 8;
    const int abase = p * 2048 + ww * 32 + sw8;     // + vv*256 per mf
    __builtin_amdgcn_s_setprio(1);
#pragma unroll
    for (int mf = 0; mf < 4; ++mf) {
      const int vv = mf * 2 + v0 + dv;
      const bool ok = wok && ((unsigned)vv < 8u);
      // address-select: invalid lanes broadcast-read the zero slot
      const int adh = ok ? (abase + vv * 256) : ZSLOT;
      const int adl = ok ? (abase + vv * 256 + 8192) : ZSLOT;
      f16x8 ah = *(const f16x8*)&lsAll[adh];
      f16x8 al = *(const f16x8*)&lsAll[adl];
#pragma unroll
      for (int nf = 0; nf < 4; ++nf) {
        aA[mf][nf] = MFMA16(ah, bh[nf], aA[mf][nf]);
        aB[mf][nf] = MFMA16(ah, bl[nf], aB[mf][nf]);
        aB[mf][nf] = MFMA16(al, bh[nf], aB[mf][nf]);
      }
    }
    __builtin_amdgcn_s_setprio(0);
  };

  // prologue: zero slot + first stages
  if (tid == 0) *(f32x4*)&lsAll[ZSLOT] = (f32x4){0.f, 0.f, 0.f, 0.f};
  stageA(0);
  stageB(0, 0, 0);
  __syncthreads();

  int cur = 0;
#pragma unroll 1
  for (int kb = 0; kb < KB; ++kb) {
#pragma unroll 1
    for (int og = 0; og < 3; ++og) {
      const int du = og - 1;
#pragma unroll
      for (int oi = 0; oi < 9; ++oi) {
        const int o = og * 9 + oi;                  // og runtime, oi literal
        if (o < 26)           stageB(o + 1, kb, cur ^ 1);
        else if (kb + 1 < KB) stageB(0, kb + 1, cur ^ 1);
        compute(du, oi / 3 - 1, oi % 3 - 1, cur);   // dv,dw compile-time
        __syncthreads();
        cur ^= 1;
      }
    }
    if (kb + 1 < KB) {
      stageA(kb + 1);
      __syncthreads();
    }
  }

  // epilogue: two row-half passes through LDS (padded stride, conflict-free)
  float* sY = (float*)lsAll;            // [64][132]
#pragma unroll 1
  for (int rh = 0; rh < 2; ++rh) {
    if (wm == rh) {
#pragma unroll
      for (int mf = 0; mf < 4; ++mf)
#pragma unroll
        for (int nf = 0; nf < 4; ++nf)
#pragma unroll
          for (int j = 0; j < 4; ++j) {
            const int row = mf * 16 + lk * 4 + j;
            const int col = wn * 64 + nf * 16 + l15;
            sY[row * 132 + col] = aA[mf][nf][j] + aB[mf][nf][j] * kDS;
          }
    }
    __syncthreads();
#pragma unroll
    for (int it = 0; it < 2; ++it) {
      const int row = it * 32 + (tid >> 3);
      const int c0 = (tid & 7) * 16;
      const long grow = (long)img * 512 + (u0 + rh) * 64 + row;
      const long gidx = yz + grow * (long)yr + coutb0 + c0;
      float yv[16];
#pragma unroll
      for (int i2 = 0; i2 < 16; ++i2) yv[i2] = sY[row * 132 + c0 + i2];
      if (ACT) {
#pragma unroll
        for (int i2 = 0; i2 < 16; ++i2) yv[i2] = gelu_exact(yv[i2]);
      }
      if (RESID) {
        f16x8 r0h = *(const f16x8*)&Yh[gidx];
        f16x8 r1h = *(const f16x8*)&Yh[gidx + 8];
        f16x8 r0l = *(const f16x8*)&Yl[gidx];
        f16x8 r1l = *(const f16x8*)&Yl[gidx + 8];
#pragma unroll
        for (int i2 = 0; i2 < 8; ++i2) {
          yv[i2] += rec2(r0h[i2], r0l[i2]);
          yv[8 + i2] += rec2(r1h[i2], r1l[i2]);
        }
      }
      f16x8 h0, h1, l0, l1;
#pragma unroll
      for (int i2 = 0; i2 < 8; ++i2) {
        f16 a, b;
        split2(yv[i2], &a, &b); h0[i2] = a; l0[i2] = b;
        split2(yv[8 + i2], &a, &b); h1[i2] = a; l1[i2] = b;
      }
      *(f16x8*)&Yh[gidx] = h0;
      *(f16x8*)&Yh[gidx + 8] = h1;
      *(f16x8*)&Yl[gidx] = l0;
      *(f16x8*)&Yl[gidx + 8] = l1;
    }
    __syncthreads();
  }
}

// ---------------- plain GEMM (classifier), pair in, pair or f32 out --------
template <int K_, int COUT, bool F32OUT>
__global__ __launch_bounds__(256) void gemm_kernel(
    const f16* __restrict__ Xh, const f16* __restrict__ Xl,
    const f16* __restrict__ Wh, const f16* __restrict__ Wl,
    const float* __restrict__ bias,
    f16* __restrict__ Yh, f16* __restrict__ Yl, float* __restrict__ Yf) {
  const int m0 = blockIdx.x * 64;
  const int coutb = blockIdx.y * 64;
  const int tid = threadIdx.x;
  const int wid = tid >> 6, lane = tid & 63;
  const int l15 = lane & 15, lk = lane >> 4;
  const int arow = m0 + wid * 16 + l15;

  f32x4 accA[4], accB[4];
#pragma unroll
  for (int cg = 0; cg < 4; ++cg) {
    float bv = bias[coutb + cg * 16 + l15];
    accA[cg] = (f32x4){bv, bv, bv, bv};
    accB[cg] = (f32x4){0.f, 0.f, 0.f, 0.f};
  }
  const f16* pah = Xh + (long)arow * K_ + lk * 8;
  const f16* pal = Xl + (long)arow * K_ + lk * 8;
  const f16* pbh = Wh + ((long)coutb + l15) * K_ + lk * 8;
  const f16* pbl = Wl + ((long)coutb + l15) * K_ + lk * 8;
#pragma unroll 2
  for (int kb = 0; kb < K_ / 32; ++kb) {
    f16x8 ah = *(const f16x8*)(pah + kb * 32);
    f16x8 al = *(const f16x8*)(pal + kb * 32);
#pragma unroll
    for (int cg = 0; cg < 4; ++cg) {
      f16x8 bh = *(const f16x8*)(pbh + (long)cg * 16 * K_ + kb * 32);
      f16x8 bl = *(const f16x8*)(pbl + (long)cg * 16 * K_ + kb * 32);
      accA[cg] = MFMA16(ah, bh, accA[cg]);
      accB[cg] = MFMA16(ah, bl, accB[cg]);
      accB[cg] = MFMA16(al, bh, accB[cg]);
    }
  }
  const long ybase = ((long)m0 + wid * 16) * (long)COUT + coutb;
#pragma unroll
  for (int cg = 0; cg < 4; ++cg)
#pragma unroll
    for (int j = 0; j < 4; ++j) {
      int r = lk * 4 + j;
      float y = accA[cg][j] + accB[cg][j] * kDS;
      long idx = ybase + (long)r * COUT + cg * 16 + l15;
      if (F32OUT) Yf[idx] = y;
      else        split2(y, Yh + idx, Yl + idx);
    }
}

// ---------------- attention on interleaved QKV [tok][768] pairs ------------
__global__ __launch_bounds__(256) void attn_kernel(
    f16* __restrict__ QKVh, f16* __restrict__ QKVl) {
  __shared__ float sq[4][16][33];
  __shared__ float sk[4][16][33];
  __shared__ float sv[4][16][33];
  __shared__ float ss[4][16][17];
  const int wid = threadIdx.x >> 6, lane = threadIdx.x & 63;
  const int p = blockIdx.x * 4 + wid;
  const int cs = p >> 12;
  const int loc = p & 4095;
  const int nh = loc >> 9;
  const int vox = loc & 511;
  const int srow = lane >> 2;
  const int dp = (lane & 3) * 8;
  const long sbase = (long)cs * 6291456;
  const long base = sbase + ((long)(srow * 512 + vox)) * 768 + nh * 32 + dp;

  {
    f16x8 qh = *(const f16x8*)(QKVh + base);
    f16x8 ql = *(const f16x8*)(QKVl + base);
    f16x8 kh = *(const f16x8*)(QKVh + base + 256);
    f16x8 kl = *(const f16x8*)(QKVl + base + 256);
    f16x8 vh = *(const f16x8*)(QKVh + base + 512);
    f16x8 vl = *(const f16x8*)(QKVl + base + 512);
#pragma unroll
    for (int j = 0; j < 8; ++j) {
      sq[wid][srow][dp + j] = rec2(qh[j], ql[j]);
      sk[wid][srow][dp + j] = rec2(kh[j], kl[j]);
      sv[wid][srow][dp + j] = rec2(vh[j], vl[j]);
    }
  }
  __syncthreads();
#pragma unroll
  for (int pp = 0; pp < 4; ++pp) {
    int pr = lane * 4 + pp;
    int qi = pr >> 4, kt = pr & 15;
    float s = 0.f;
#pragma unroll
    for (int d = 0; d < 32; ++d) s += sq[wid][qi][d] * sk[wid][kt][d];
    bool allowed = (kt < 8) || (kt <= qi);
    ss[wid][qi][kt] = allowed ? s * 0.17677669529663687f : -1e30f;
  }
  __syncthreads();
  if (lane < 16) {
    float m = -1e30f;
#pragma unroll
    for (int t = 0; t < 16; ++t) m = fmaxf(m, ss[wid][lane][t]);
    float ex[16];
    float sum = 0.f;
#pragma unroll
    for (int t = 0; t < 16; ++t) { ex[t] = expf(ss[wid][lane][t] - m); sum += ex[t]; }
    float inv = 1.0f / sum;
#pragma unroll
    for (int t = 0; t < 16; ++t) ss[wid][lane][t] = ex[t] * inv;
  }
  __syncthreads();
  float o[8] = {0, 0, 0, 0, 0, 0, 0, 0};
#pragma unroll
  for (int t = 0; t < 16; ++t) {
    float a = ss[wid][srow][t];
#pragma unroll
    for (int j = 0; j < 8; ++j) o[j] += a * sv[wid][t][dp + j];
  }
#pragma unroll
  for (int j = 0; j < 8; ++j) split2(o[j], QKVh + base + j, QKVl + base + j);
}

// ---------------- LayerNorm in place on H pair -----------------------------
__global__ __launch_bounds__(256) void ln_kernel(
    f16* __restrict__ Hh, f16* __restrict__ Hl,
    const float* __restrict__ gam, const float* __restrict__ bet) {
  const int wid = threadIdx.x >> 6, lane = threadIdx.x & 63;
  const long tok = (long)blockIdx.x * 4 + wid;
  const long base = tok * 256 + lane * 4;
  f16x4 hh = *(const f16x4*)(Hh + base);
  f16x4 hl = *(const f16x4*)(Hl + base);
  float v0 = rec2(hh[0], hl[0]), v1 = rec2(hh[1], hl[1]);
  float v2 = rec2(hh[2], hl[2]), v3 = rec2(hh[3], hl[3]);
  float mu = wave_sum_f(v0 + v1 + v2 + v3) * (1.0f / 256.0f);
  float d0 = v0 - mu, d1 = v1 - mu, d2 = v2 - mu, d3 = v3 - mu;
  float var = wave_sum_f(d0 * d0 + d1 * d1 + d2 * d2 + d3 * d3) * (1.0f / 256.0f);
  float rs = rsqrtf(var + 1e-5f);
  float4 gv = *(const float4*)(gam + lane * 4);
  float4 bv = *(const float4*)(bet + lane * 4);
  float y0 = d0 * rs * gv.x + bv.x, y1 = d1 * rs * gv.y + bv.y;
  float y2 = d2 * rs * gv.z + bv.z, y3 = d3 * rs * gv.w + bv.w;
  f16x4 oh, ol;
  f16 a, b2;
  split2(y0, &a, &b2); oh[0] = a; ol[0] = b2;
  split2(y1, &a, &b2); oh[1] = a; ol[1] = b2;
  split2(y2, &a, &b2); oh[2] = a; ol[2] = b2;
  split2(y3, &a, &b2); oh[3] = a; ol[3] = b2;
  *(f16x4*)(Hh + base) = oh;
  *(f16x4*)(Hl + base) = ol;
}

// ---------------- classifier LN + GELU in-place (pairs) --------------------
__global__ __launch_bounds__(256) void ln_gelu_kernel(
    f16* __restrict__ Zh, f16* __restrict__ Zl,
    const float* __restrict__ gam, const float* __restrict__ bet) {
  const int wid = threadIdx.x >> 6, lane = threadIdx.x & 63;
  const long tok = (long)blockIdx.x * 4 + wid;
  const long base = tok * 256 + lane * 4;
  f16x4 hh = *(const f16x4*)(Zh + base);
  f16x4 hl = *(const f16x4*)(Zl + base);
  float v0 = rec2(hh[0], hl[0]), v1 = rec2(hh[1], hl[1]);
  float v2 = rec2(hh[2], hl[2]), v3 = rec2(hh[3], hl[3]);
  float mu = wave_sum_f(v0 + v1 + v2 + v3) * (1.0f / 256.0f);
  float d0 = v0 - mu, d1 = v1 - mu, d2 = v2 - mu, d3 = v3 - mu;
  float var = wave_sum_f(d0 * d0 + d1 * d1 + d2 * d2 + d3 * d3) * (1.0f / 256.0f);
  float rs = rsqrtf(var + 1e-5f);
  float4 gv = *(const float4*)(gam + lane * 4);
  float4 bv = *(const float4*)(bet + lane * 4);
  float y0 = gelu_exact(d0 * rs * gv.x + bv.x);
  float y1 = gelu_exact(d1 * rs * gv.y + bv.y);
  float y2 = gelu_exact(d2 * rs * gv.z + bv.z);
  float y3 = gelu_exact(d3 * rs * gv.w + bv.w);
  f16x4 oh, ol;
  f16 a, b2;
  split2(y0, &a, &b2); oh[0] = a; ol[0] = b2;
  split2(y1, &a, &b2); oh[1] = a; ol[1] = b2;
  split2(y2, &a, &b2); oh[2] = a; ol[2] = b2;
  split2(y3, &a, &b2); oh[3] = a; ol[3] = b2;
  *(f16x4*)(Zh + base) = oh;
  *(f16x4*)(Zl + base) = ol;
}

// ---------------- classifier token gather (pair copy) ----------------------
__global__ __launch_bounds__(256) void gather_kernel(
    const f16* __restrict__ Hh, const f16* __restrict__ Hl, int n,
    f16* __restrict__ Xh, f16* __restrict__ Xl) {
  const int tc = blockIdx.x;       // (s2*3+c)*512+vox
  const int e = threadIdx.x;
  const int s2 = tc / 1536;
  int r = tc - s2 * 1536;
  const int c = r >> 9;
  const int vox = r & 511;
  const int g = n * 3 + c;
  const int s = 7 + s2;
  const long src = ((long)(g * 16 + s) * 512 + vox) * 256 + e;
  const long dst = (long)tc * 256 + e;
  Xh[dst] = Hh[src];
  Xl[dst] = Hl[src];
}

// ---------------- score transpose: Z2[t][k] -> out[k][t] (per n) -----------
__global__ __launch_bounds__(256) void transpose_kernel(
    const float* __restrict__ Z2, float* __restrict__ out) {
  __shared__ float tile[32][33];
  const int t0 = blockIdx.x * 32;
  const int k0 = blockIdx.y * 32;
  const int tx = threadIdx.x & 31;
  const int ty = threadIdx.x >> 5;
#pragma unroll
  for (int i = 0; i < 32; i += 8)
    tile[ty + i][tx] = Z2[((long)(t0 + ty + i)) * 512 + k0 + tx];
  __syncthreads();
#pragma unroll
  for (int i = 0; i < 32; i += 8)
    out[((long)(k0 + ty + i)) * 13824 + t0 + tx] = tile[tx][ty + i];
}

// ---------------- loss + pred (per n chunk) --------------------------------
__global__ __launch_bounds__(256) void loss_pred_kernel(
    const float* __restrict__ Z2, const int* __restrict__ ncode,
    float* __restrict__ pred, float* __restrict__ partial) {
  __shared__ float sh[4];
  const int wid = threadIdx.x >> 6, lane = threadIdx.x & 63;
  const int tok = blockIdx.x * 4 + wid;
  const float* row = Z2 + (long)tok * 512;
  float4 a = *(const float4*)(row + lane * 8);
  float4 b = *(const float4*)(row + lane * 8 + 4);
  float vals[8] = {a.x, a.y, a.z, a.w, b.x, b.y, b.z, b.w};
  float mx = vals[0];
  int mi = lane * 8;
#pragma unroll
  for (int j = 1; j < 8; ++j)
    if (vals[j] > mx) { mx = vals[j]; mi = lane * 8 + j; }
#pragma unroll
  for (int m = 1; m < 64; m <<= 1) {
    float ox = __shfl_xor(mx, m);
    int oi = __shfl_xor(mi, m);
    if (ox > mx || (ox == mx && oi < mi)) { mx = ox; mi = oi; }
  }
  float se = 0.f;
#pragma unroll
  for (int j = 0; j < 8; ++j) se += expf(vals[j] - mx);
  se = wave_sum_f(se);
  if (lane == 0) {
    int tgt = ncode[tok];
    float nll = mx + logf(se) - row[tgt];
    pred[tok] = (float)mi;
    sh[wid] = nll;
  }
  __syncthreads();
  if (threadIdx.x == 0) partial[blockIdx.x] = sh[0] + sh[1] + sh[2] + sh[3];
}

__global__ __launch_bounds__(256) void loss_final_kernel(
    const float* __restrict__ partial, float* __restrict__ out) {
  __shared__ float sh[4];
  float s = 0.f;
  for (int i = threadIdx.x; i < 6912; i += 256) s += partial[i];
  s = wave_sum_f(s);
  if ((threadIdx.x & 63) == 0) sh[threadIdx.x >> 6] = s;
  __syncthreads();
  if (threadIdx.x == 0) out[0] = (sh[0] + sh[1] + sh[2] + sh[3]) * (1.0f / 27648.0f);
}

// ---------------- sentinel fill --------------------------------------------
__global__ __launch_bounds__(256) void fill_kernel(float* __restrict__ p, long n, float v) {
  long i = (long)blockIdx.x * 256 + threadIdx.x;
  if (i < n) p[i] = v;
}

// ===========================================================================
extern "C" void kernel_launch(void* const* d_in, const int* in_sizes, int n_in,
                              void* d_out, int out_size, void* d_ws, size_t ws_size,
                              hipStream_t stream) {
  const int* code   = (const int*)d_in[0];
  const int* ncode  = (const int*)d_in[1];
  const float* emb  = (const float*)d_in[2];
  const float* pos  = (const float*)d_in[3];
  const float* Wq   = (const float*)d_in[4];
  const float* bq   = (const float*)d_in[5];
  const float* Wk   = (const float*)d_in[6];
  const float* bk   = (const float*)d_in[7];
  const float* Wv   = (const float*)d_in[8];
  const float* bv   = (const float*)d_in[9];
  const float* Wo   = (const float*)d_in[10];
  const float* bo   = (const float*)d_in[11];
  const float* ln1g = (const float*)d_in[12];
  const float* ln1b = (const float*)d_in[13];
  const float* ln2g = (const float*)d_in[14];
  const float* ln2b = (const float*)d_in[15];
  const float* Wc1  = (const float*)d_in[16];
  const float* bc1  = (const float*)d_in[17];
  const float* Wc2  = (const float*)d_in[18];
  const float* bc2  = (const float*)d_in[19];
  const float* cW1  = (const float*)d_in[20];
  const float* cb1  = (const float*)d_in[21];
  const float* clng = (const float*)d_in[22];
  const float* clnb = (const float*)d_in[23];
  const float* cW2  = (const float*)d_in[24];
  const float* cb2  = (const float*)d_in[25];
  float* out = (float*)d_out;
  (void)in_sizes; (void)n_in; (void)out_size;

  // sizes (f16 units)
  const long WSLOT = 5308416;    // 27*768*256 (max per-conv weight, QKV fused)
  const long HSL   = 2097152;    // per-slice H per comp
  const long QSL   = 6291456;    // per-slice QKV interleaved per comp
  const long T1SL  = 4194304;    // per-slice T1 per comp
  const long CLMIN = 21233664;   // classifier slab minimum

  auto needf = [&](int ns) -> size_t {
    long slab = (long)ns * 2 * QSL;
    if (slab < CLMIN) slab = CLMIN;
    return (size_t)(2 * WSLOT + 2 * 12582912L + slab) * 2 + 6912 * 4 + 768 * 4 + 4096;
  };
  int NS = 0;
  if      (ws_size >= needf(6)) NS = 6;
  else if (ws_size >= needf(3)) NS = 3;
  else if (ws_size >= needf(2)) NS = 2;
  else if (ws_size >= needf(1)) NS = 1;
  if (NS == 0) {
    fill_kernel<<<dim3(109), 256, 0, stream>>>(out + kSC, 27649, -1.0f);
    return;
  }
  long slab_f16 = (long)NS * 2 * QSL;
  if (slab_f16 < CLMIN) slab_f16 = CLMIN;

  f16* wh = (f16*)d_ws;
  f16* wl = wh + WSLOT;
  f16* Hh = wl + WSLOT;
  f16* Hl = Hh + 12582912;
  f16* S  = Hl + 12582912;
  float* partial = (float*)(S + slab_f16);
  float* bcat = partial + 6912;

  const size_t WQKVO = 27u * 256 * 256;
  const size_t WC1SZ = 27u * 256 * 512;
  const size_t WC2SZ = 27u * 512 * 256;

  embed_kernel<<<dim3(49152), 256, 0, stream>>>(code, ncode, emb, pos, Hh, Hl);

  const int nchunk = 6 / NS;
  f16* qkvh = S;
  f16* qkvl = S + (long)NS * QSL;
  f16* t1h  = S;
  f16* t1l  = S + (long)NS * T1SL;

  for (int l = 0; l < 2; ++l) {
    const float* wq = Wq + (size_t)l * WQKVO;
    const float* wk = Wk + (size_t)l * WQKVO;
    const float* wv = Wv + (size_t)l * WQKVO;
    const float* wo = Wo + (size_t)l * WQKVO;
    const float* wc1 = Wc1 + (size_t)l * WC1SZ;
    const float* wc2 = Wc2 + (size_t)l * WC2SZ;
    bpack_kernel<<<dim3(3), 256, 0, stream>>>(bq + l * 256, bk + l * 256, bv + l * 256, bcat);
    for (int ch = 0; ch < nchunk; ++ch) {
      f16* Xh = Hh + (long)ch * NS * HSL;
      f16* Xl = Hl + (long)ch * NS * HSL;
      // fused QKV conv
      wsplit_kernel<<<dim3(6912), 256, 0, stream>>>(wq, wh, wl, 27, 256, 256, 768, 0);
      wsplit_kernel<<<dim3(6912), 256, 0, stream>>>(wk, wh, wl, 27, 256, 256, 768, 256);
      wsplit_kernel<<<dim3(6912), 256, 0, stream>>>(wv, wh, wl, 27, 256, 256, 768, 512);
      conv16_kernel<256, 768, 0, 0><<<dim3(64 * 6 * NS), 256, 0, stream>>>(
          Xh, Xl, HSL, 256, wh, wl, bcat, qkvh, qkvl, QSL, 768, NS);
      attn_kernel<<<dim3(NS * 1024), 256, 0, stream>>>(qkvh, qkvl);
      // O projection with fused residual into H
      wsplit_kernel<<<dim3(6912), 256, 0, stream>>>(wo, wh, wl, 27, 256, 256, 256, 0);
      conv16_kernel<256, 256, 0, 1><<<dim3(64 * 2 * NS), 256, 0, stream>>>(
          qkvh, qkvl, QSL, 768, wh, wl, bo + l * 256, Xh, Xl, HSL, 256, NS);
      ln_kernel<<<dim3(2048 * NS), 256, 0, stream>>>(Xh, Xl, ln1g + l * 256, ln1b + l * 256);
      // FFN1 with fused gelu
      wsplit_kernel<<<dim3(13824), 256, 0, stream>>>(wc1, wh, wl, 27, 256, 512, 512, 0);
      conv16_kernel<256, 512, 1, 0><<<dim3(64 * 4 * NS), 256, 0, stream>>>(
          Xh, Xl, HSL, 256, wh, wl, bc1 + l * 512, t1h, t1l, T1SL, 512, NS);
      // FFN2 with fused residual
      wsplit_kernel<<<dim3(13824), 256, 0, stream>>>(wc2, wh, wl, 27, 512, 256, 256, 0);
      conv16_kernel<512, 256, 0, 1><<<dim3(64 * 2 * NS), 256, 0, stream>>>(
          t1h, t1l, T1SL, 512, wh, wl, bc2 + l * 256, Xh, Xl, HSL, 256, NS);
      ln_kernel<<<dim3(2048 * NS), 256, 0, stream>>>(Xh, Xl, ln2g + l * 256, ln2b + l * 256);
    }
  }

  // ---- classifier, chunked by n ----
  for (int n = 0; n < 2; ++n) {
    f16* Z1h = S;
    f16* Z1l = S + 3538944;
    f16* Xch = S + 7077888;
    f16* Xcl = S + 10616832;
    float* Z2 = (float*)(S + 7077888);   // overwrites Xc (dead after gemm1)
    gather_kernel<<<dim3(13824), 256, 0, stream>>>(Hh, Hl, n, Xch, Xcl);
    wsplit_kernel<<<dim3(256), 256, 0, stream>>>(cW1, wh, wl, 1, 256, 256, 256, 0);
    gemm_kernel<256, 256, false><<<dim3(216, 4), 256, 0, stream>>>(Xch, Xcl, wh, wl, cb1, Z1h, Z1l, nullptr);
    ln_gelu_kernel<<<dim3(3456), 256, 0, stream>>>(Z1h, Z1l, clng, clnb);
    wsplit_kernel<<<dim3(512), 256, 0, stream>>>(cW2, wh, wl, 1, 256, 512, 512, 0);
    gemm_kernel<256, 512, true><<<dim3(216, 8), 256, 0, stream>>>(Z1h, Z1l, wh, wl, cb2, nullptr, nullptr, Z2);
    transpose_kernel<<<dim3(432, 16), 256, 0, stream>>>(Z2, out + (long)n * 512 * 13824);
    loss_pred_kernel<<<dim3(3456), 256, 0, stream>>>(Z2, ncode + n * 13824,
                                                     out + kSC + 1 + n * 13824, partial + n * 3456);
  }
  loss_final_kernel<<<dim3(1), 256, 0, stream>>>(partial, out + kSC);
}